// Round 1
// baseline (3189.602 us; speedup 1.0000x reference)
//
#include <hip/hip_runtime.h>
#include <hip/hip_bf16.h>
#include <math.h>

static constexpr int BB = 4;
static constexpr int NN = 20000;
static constexpr int CC = 256;
static constexpr int SS = 1024;   // NUM_SAMPLE
static constexpr int NV = 300;    // NUM_VIEW

// output offsets (floats) in d_out, concatenated in reference return order
static constexpr size_t O0 = 0;                     // objectness (B,2,N)
static constexpr size_t O1 = O0 + (size_t)BB*2*NN;  // graspness (B,N)
static constexpr size_t O2 = O1 + (size_t)BB*NN;    // graspable_xyz (B,S,3)
static constexpr size_t O3 = O2 + (size_t)BB*SS*3;  // graspable_inds (B,S) as float
static constexpr size_t O4 = O3 + (size_t)BB*SS;    // graspable_features (B,C,S)
static constexpr size_t O5 = O4 + (size_t)BB*CC*SS; // fp2_graspness (B,S)
static constexpr size_t O6 = O5 + (size_t)BB*SS;    // vp_xyz (B,S,3)
static constexpr size_t O7 = O6 + (size_t)BB*SS*3;  // top_view_inds (B,S) as float
static constexpr size_t O8 = O7 + (size_t)BB*SS;    // vp_rot (B,S,3,3)

// ---------------------------------------------------------------------------
// Fused GEMM: out3ch = W2(3x256) @ relu(bn(W1(256x256) @ X + b1)) + b2
// mode 0: write objectness/graspness/mask   mode 1: write vp_xyz (B,S,3)
// ---------------------------------------------------------------------------
static constexpr int TN = 64;     // columns per block
static constexpr int KC = 32;     // k-chunk
static constexpr int SW_LD = 260; // padded LDS row for sW[k][m]
static constexpr int PS_LD = 68;  // padded LDS row for psum

__global__ __launch_bounds__(256, 2) void gemm_fused(
    const float* __restrict__ X, int ncols, int cstride,
    const float* __restrict__ W1, const float* __restrict__ B1v,
    const float* __restrict__ Gv, const float* __restrict__ BEv,
    const float* __restrict__ Mv, const float* __restrict__ Vv,
    const float* __restrict__ W2, const float* __restrict__ B2v,
    int mode, float* __restrict__ o0, float* __restrict__ o1,
    unsigned char* __restrict__ maskp, float* __restrict__ vp)
{
    __shared__ alignas(16) char smem_raw[KC*SW_LD*4 + KC*TN*4]; // 41472 B (phase2 aliases)
    float* sW   = (float*)smem_raw;                       // [KC][SW_LD]
    float* sF   = (float*)(smem_raw + KC*SW_LD*4);        // [KC][TN]
    float* psum = (float*)smem_raw;                       // [3][32][PS_LD] = 26112 B
    float* gout = (float*)(smem_raw + 3*32*PS_LD*4);      // [3][64]

    const int t  = threadIdx.x;
    const int b  = blockIdx.y;
    const int n0 = blockIdx.x * TN;
    const int tm = t & 31;   // 32 groups along M (8 rows each)
    const int tn = t >> 5;   // 8 groups along N (8 cols each)

    const float* Xb = X + (size_t)b * CC * cstride;

    float acc[8][8];
#pragma unroll
    for (int i = 0; i < 8; ++i)
#pragma unroll
        for (int j = 0; j < 8; ++j) acc[i][j] = 0.f;

    for (int k0 = 0; k0 < CC; k0 += KC) {
        // stage W1 tile (256 x KC), transposed into sW[k][m]
#pragma unroll
        for (int r = 0; r < (CC*KC)/256; ++r) {
            int idx = r*256 + t;
            int m  = idx >> 5;
            int kk = idx & 31;
            sW[kk*SW_LD + m] = W1[m*CC + k0 + kk];
        }
        // stage X tile (KC x 64)
#pragma unroll
        for (int r = 0; r < (KC*TN)/256; ++r) {
            int idx = r*256 + t;
            int kk = idx >> 6;
            int j  = idx & 63;
            int col = n0 + j;
            float v = 0.f;
            if (col < ncols) v = Xb[(size_t)(k0+kk)*cstride + col];
            sF[kk*TN + j] = v;
        }
        __syncthreads();
#pragma unroll 8
        for (int kk = 0; kk < KC; ++kk) {
            const float4 a0 = *(const float4*)(sW + kk*SW_LD + tm*8);
            const float4 a1 = *(const float4*)(sW + kk*SW_LD + tm*8 + 4);
            const float4 f0 = *(const float4*)(sF + kk*TN + tn*8);
            const float4 f1 = *(const float4*)(sF + kk*TN + tn*8 + 4);
            float av[8] = {a0.x,a0.y,a0.z,a0.w,a1.x,a1.y,a1.z,a1.w};
            float bv[8] = {f0.x,f0.y,f0.z,f0.w,f1.x,f1.y,f1.z,f1.w};
#pragma unroll
            for (int i = 0; i < 8; ++i)
#pragma unroll
                for (int j = 0; j < 8; ++j)
                    acc[i][j] = fmaf(av[i], bv[j], acc[i][j]);
        }
        __syncthreads();
    }

    // epilogue: bias + bn + relu in registers, partial W2 contraction
    float part[3][8];
#pragma unroll
    for (int r = 0; r < 3; ++r)
#pragma unroll
        for (int j = 0; j < 8; ++j) part[r][j] = 0.f;

#pragma unroll
    for (int i = 0; i < 8; ++i) {
        int m = tm*8 + i;
        float scale = __fdiv_rn(Gv[m], __fsqrt_rn(__fadd_rn(Vv[m], 1e-5f)));
        float shift = __fsub_rn(BEv[m], __fmul_rn(Mv[m], scale));
        float w0 = W2[m], w1 = W2[CC + m], w2 = W2[2*CC + m];
        float b1m = B1v[m];
#pragma unroll
        for (int j = 0; j < 8; ++j) {
            float x = __fadd_rn(acc[i][j], b1m);
            float y = __fadd_rn(__fmul_rn(x, scale), shift);
            float h = y > 0.f ? y : 0.f;
            part[0][j] = fmaf(w0, h, part[0][j]);
            part[1][j] = fmaf(w1, h, part[1][j]);
            part[2][j] = fmaf(w2, h, part[2][j]);
        }
    }
#pragma unroll
    for (int r = 0; r < 3; ++r) {
        float4 p0 = {part[r][0], part[r][1], part[r][2], part[r][3]};
        float4 p1 = {part[r][4], part[r][5], part[r][6], part[r][7]};
        *(float4*)(psum + (r*32 + tm)*PS_LD + tn*8)     = p0;
        *(float4*)(psum + (r*32 + tm)*PS_LD + tn*8 + 4) = p1;
    }
    __syncthreads();
    if (t < 192) {
        int r = t >> 6, col = t & 63;
        float s = 0.f;
#pragma unroll
        for (int w = 0; w < 32; ++w) s = __fadd_rn(s, psum[(r*32 + w)*PS_LD + col]);
        float tot = __fadd_rn(s, B2v[r]);
        if (mode == 0) {
            gout[r*64 + col] = tot;
        } else {
            vp[((size_t)b*SS + n0 + col)*3 + r] = tot;
        }
    }
    if (mode == 0) {
        __syncthreads();
        if (t < 64) {
            int n = n0 + t;
            if (n < ncols) {
                float v0 = gout[t], v1 = gout[64 + t], v2 = gout[128 + t];
                o0[(size_t)b*2*ncols + n]         = v0;
                o0[(size_t)b*2*ncols + ncols + n] = v1;
                o1[(size_t)b*ncols + n]           = v2;
                maskp[(size_t)b*ncols + n] = (v2 > 0.1f && v1 > v0) ? 1 : 0;
            }
        }
    }
}

// ---------------------------------------------------------------------------
// Order-preserving stream compaction of masked-in candidates
// ---------------------------------------------------------------------------
__global__ __launch_bounds__(256) void compact_kernel(
    const unsigned char* __restrict__ maskp, const float* __restrict__ xyz,
    int* __restrict__ cntp, int* __restrict__ corig,
    float* __restrict__ cx, float* __restrict__ cy, float* __restrict__ cz)
{
    const int b = blockIdx.x;
    const int t = threadIdx.x;
    __shared__ int wsum[4];
    __shared__ int running;
    if (t == 0) running = 0;
    __syncthreads();
    const unsigned char* mb = maskp + (size_t)b*NN;
    const size_t bofs = (size_t)b*NN;
    for (int base = 0; base < NN; base += 256) {
        int i = base + t;
        int m = (i < NN) ? (int)mb[i] : 0;
        unsigned long long bal = __ballot(m != 0);
        int lane = t & 63, w = t >> 6;
        int pre = __popcll(bal & ((1ull << lane) - 1ull));
        if (lane == 0) wsum[w] = __popcll(bal);
        __syncthreads();
        int offs = running;
        for (int ww = 0; ww < w; ++ww) offs += wsum[ww];
        if (m) {
            int pos = offs + pre;
            corig[bofs + pos] = i;
            cx[bofs + pos] = xyz[(bofs + i)*3 + 0];
            cy[bofs + pos] = xyz[(bofs + i)*3 + 1];
            cz[bofs + pos] = xyz[(bofs + i)*3 + 2];
        }
        __syncthreads();
        if (t == 0) running += wsum[0] + wsum[1] + wsum[2] + wsum[3];
    }
    __syncthreads();
    if (t == 0) cntp[b] = running;
}

// ---------------------------------------------------------------------------
// Masked FPS over compacted candidates, candidates in registers
// ---------------------------------------------------------------------------
static constexpr int FPS_T = 512;
static constexpr int REG = 40;  // ceil(20000/512)

__global__ __launch_bounds__(512, 2) void fps_kernel(
    const int* __restrict__ cntp, const int* __restrict__ corig,
    const float* __restrict__ cx, const float* __restrict__ cy, const float* __restrict__ cz,
    float* __restrict__ o3, int* __restrict__ oi)
{
    const int b = blockIdx.x;
    const int t = threadIdx.x;
    const int cnt = cntp[b];
    const size_t bofs = (size_t)b*NN;
    float* o3b = o3 + (size_t)b*SS;
    int*   oib = oi + (size_t)b*SS;

    if (cnt <= 0) {
        for (int s = t; s < SS; s += FPS_T) { o3b[s] = 0.f; oib[s] = 0; }
        return;
    }

    float X[REG], Y[REG], Z[REG], D[REG];
#pragma unroll
    for (int j = 0; j < REG; ++j) {
        int g = t + (j << 9);
        if (g >= cnt) break;
        X[j] = cx[bofs + g];
        Y[j] = cy[bofs + g];
        Z[j] = cz[bofs + g];
        D[j] = 1e10f;
    }

    __shared__ float swv[2][8];
    __shared__ int   swi[2][8];

    float px = cx[bofs], py = cy[bofs], pz = cz[bofs];
    if (t == 0) { int org = corig[bofs]; o3b[0] = (float)org; oib[0] = org; }

    const int wave = t >> 6, lane = t & 63;

    for (int it = 1; it < SS; ++it) {
        float bv = -INFINITY; int bi = 0x7fffffff;
#pragma unroll
        for (int j = 0; j < REG; ++j) {
            int g = t + (j << 9);
            if (g >= cnt) break;
            float dx = __fsub_rn(X[j], px);
            float dy = __fsub_rn(Y[j], py);
            float dz = __fsub_rn(Z[j], pz);
            float d  = __fadd_rn(__fadd_rn(__fmul_rn(dx,dx), __fmul_rn(dy,dy)), __fmul_rn(dz,dz));
            float dn = fminf(D[j], d);
            D[j] = dn;
            if (dn > bv) { bv = dn; bi = g; }
        }
        // wave butterfly argmax (tie -> lowest compacted index)
#pragma unroll
        for (int off = 32; off > 0; off >>= 1) {
            float ov  = __shfl_xor(bv, off, 64);
            int   oix = __shfl_xor(bi, off, 64);
            if (ov > bv || (ov == bv && oix < bi)) { bv = ov; bi = oix; }
        }
        int par = it & 1;
        if (lane == 0) { swv[par][wave] = bv; swi[par][wave] = bi; }
        __syncthreads();
        float wv = swv[par][0]; int wi = swi[par][0];
#pragma unroll
        for (int w = 1; w < 8; ++w) {
            float v2 = swv[par][w]; int i2 = swi[par][w];
            if (v2 > wv || (v2 == wv && i2 < wi)) { wv = v2; wi = i2; }
        }
        px = cx[bofs + wi]; py = cy[bofs + wi]; pz = cz[bofs + wi];
        if (t == 0) { int org = corig[bofs + wi]; o3b[it] = (float)org; oib[it] = org; }
    }
}

// ---------------------------------------------------------------------------
// Gathers: graspable_xyz, graspable_features, fp2_graspness
// ---------------------------------------------------------------------------
__global__ __launch_bounds__(256) void gather_kernel(
    const float* __restrict__ xyz, const float* __restrict__ feats,
    const float* __restrict__ grasp, const int* __restrict__ inds,
    float* __restrict__ o2, float* __restrict__ o4, float* __restrict__ o5)
{
    int e = blockIdx.x * 256 + threadIdx.x;   // B*C*S = 1,048,576 exactly
    int b = e >> 18;
    int r = e & ((1 << 18) - 1);
    int c = r >> 10;
    int s = r & 1023;
    int idx = inds[(b << 10) + s];
    o4[e] = feats[((size_t)b*CC + c)*NN + idx];
    if (c == 0) {
        o5[(b << 10) + s] = grasp[(size_t)b*NN + idx];
        size_t src = ((size_t)b*NN + idx)*3;
        size_t dst = ((size_t)(b << 10) + s)*3;
        o2[dst + 0] = xyz[src + 0];
        o2[dst + 1] = xyz[src + 1];
        o2[dst + 2] = xyz[src + 2];
    }
}

// ---------------------------------------------------------------------------
// top_view argmax + vp_rot
// ---------------------------------------------------------------------------
__global__ __launch_bounds__(256) void view_rot_kernel(
    const float* __restrict__ vp, float* __restrict__ o7, float* __restrict__ o8)
{
    __shared__ float tvx[NV], tvy[NV], tvz[NV];
    int t = threadIdx.x;
    for (int i = t; i < NV; i += 256) {
        double phi = (sqrt(5.0) - 1.0) * 0.5;
        double zd  = (2.0*(double)i + 1.0)/300.0 - 1.0;
        double rr  = sqrt(fmax(1.0 - zd*zd, 0.0));
        double ang = 2.0 * 3.14159265358979323846 * (double)i * phi;
        float fx = (float)(rr * cos(ang));
        float fy = (float)(rr * sin(ang));
        float fz = (float)zd;
        float nr = __fsqrt_rn(__fadd_rn(__fadd_rn(__fmul_rn(fx,fx), __fmul_rn(fy,fy)), __fmul_rn(fz,fz)));
        float dn = fmaxf(nr, 1e-8f);
        tvx[i] = __fdiv_rn(fx, dn);
        tvy[i] = __fdiv_rn(fy, dn);
        tvz[i] = __fdiv_rn(fz, dn);
    }
    __syncthreads();
    int sg = blockIdx.x * 256 + t;   // 0..4095
    float vx = vp[(size_t)sg*3 + 0];
    float vy = vp[(size_t)sg*3 + 1];
    float vz = vp[(size_t)sg*3 + 2];

    float nr = __fsqrt_rn(__fadd_rn(__fadd_rn(__fmul_rn(vx,vx), __fmul_rn(vy,vy)), __fmul_rn(vz,vz)));
    float dn = fmaxf(nr, 1e-8f);
    float ux = __fdiv_rn(vx, dn), uy = __fdiv_rn(vy, dn), uz = __fdiv_rn(vz, dn);
    float best = -INFINITY; int bidx = 0;
    for (int v = 0; v < NV; ++v) {
        float c = __fadd_rn(__fadd_rn(__fmul_rn(ux, tvx[v]), __fmul_rn(uy, tvy[v])), __fmul_rn(uz, tvz[v]));
        if (c > best) { best = c; bidx = v; }
    }
    o7[sg] = (float)bidx;

    // vp_rot: towards = -vp
    float axx = -vx, axy = -vy, axz = -vz;
    float ayx = vy, ayy = -vx, ayz = 0.f;          // ay = [-ax.y, ax.x, 0]
    float s2 = __fadd_rn(__fadd_rn(__fmul_rn(ayx,ayx), __fmul_rn(ayy,ayy)), 0.f);
    if (s2 == 0.f) { ayx = 0.f; ayy = 1.f; ayz = 0.f; }
    float an = __fsqrt_rn(__fadd_rn(__fadd_rn(__fmul_rn(axx,axx), __fmul_rn(axy,axy)), __fmul_rn(axz,axz)));
    float nx0 = __fdiv_rn(axx, an), nx1 = __fdiv_rn(axy, an), nx2 = __fdiv_rn(axz, an);
    float bn2 = __fsqrt_rn(__fadd_rn(__fadd_rn(__fmul_rn(ayx,ayx), __fmul_rn(ayy,ayy)), __fmul_rn(ayz,ayz)));
    float ny0 = __fdiv_rn(ayx, bn2), ny1 = __fdiv_rn(ayy, bn2), ny2 = __fdiv_rn(ayz, bn2);
    float nz0 = __fsub_rn(__fmul_rn(nx1, ny2), __fmul_rn(nx2, ny1));
    float nz1 = __fsub_rn(__fmul_rn(nx2, ny0), __fmul_rn(nx0, ny2));
    float nz2 = __fsub_rn(__fmul_rn(nx0, ny1), __fmul_rn(nx1, ny0));
    size_t o = (size_t)sg * 9;   // rows = (nx_i, ny_i, nz_i)
    o8[o+0] = nx0; o8[o+1] = ny0; o8[o+2] = nz0;
    o8[o+3] = nx1; o8[o+4] = ny1; o8[o+5] = nz1;
    o8[o+6] = nx2; o8[o+7] = ny2; o8[o+8] = nz2;
}

// ---------------------------------------------------------------------------
extern "C" void kernel_launch(void* const* d_in, const int* in_sizes, int n_in,
                              void* d_out, int out_size, void* d_ws, size_t ws_size,
                              hipStream_t stream) {
    const float* xyz   = (const float*)d_in[0];
    const float* feats = (const float*)d_in[1];
    const float* gh_w1 = (const float*)d_in[2];
    const float* gh_b1 = (const float*)d_in[3];
    const float* gh_g  = (const float*)d_in[4];
    const float* gh_be = (const float*)d_in[5];
    const float* gh_m  = (const float*)d_in[6];
    const float* gh_v  = (const float*)d_in[7];
    const float* gh_w2 = (const float*)d_in[8];
    const float* gh_b2 = (const float*)d_in[9];
    const float* c1_w  = (const float*)d_in[10];
    const float* c1_b  = (const float*)d_in[11];
    const float* bn_g  = (const float*)d_in[12];
    const float* bn_b  = (const float*)d_in[13];
    const float* bn_m  = (const float*)d_in[14];
    const float* bn_v  = (const float*)d_in[15];
    const float* c2_w  = (const float*)d_in[16];
    const float* c2_b  = (const float*)d_in[17];

    float* out = (float*)d_out;
    float* o0 = out + O0;
    float* o1 = out + O1;
    float* o2 = out + O2;
    float* o3 = out + O3;
    float* o4 = out + O4;
    float* o5 = out + O5;
    float* o6 = out + O6;
    float* o7 = out + O7;
    float* o8 = out + O8;

    char* ws = (char*)d_ws;
    size_t off = 0;
    auto take = [&](size_t bytes) -> char* {
        char* p = ws + off;
        off = (off + bytes + 255) & ~(size_t)255;
        return p;
    };
    unsigned char* maskp = (unsigned char*)take((size_t)BB*NN);
    int*   cntp  = (int*)take((size_t)BB*4);
    int*   corig = (int*)take((size_t)BB*NN*4);
    float* cx    = (float*)take((size_t)BB*NN*4);
    float* cy    = (float*)take((size_t)BB*NN*4);
    float* cz    = (float*)take((size_t)BB*NN*4);
    int*   indsp = (int*)take((size_t)BB*SS*4);

    // 1) fused conv+bn+relu+conv over all N points
    gemm_fused<<<dim3((NN + TN - 1)/TN, BB), 256, 0, stream>>>(
        feats, NN, NN, gh_w1, gh_b1, gh_g, gh_be, gh_m, gh_v, gh_w2, gh_b2,
        0, o0, o1, maskp, nullptr);

    // 2) compact masked-in candidates (order-preserving)
    compact_kernel<<<dim3(BB), 256, 0, stream>>>(maskp, xyz, cntp, corig, cx, cy, cz);

    // 3) sequential FPS over candidates
    fps_kernel<<<dim3(BB), FPS_T, 0, stream>>>(cntp, corig, cx, cy, cz, o3, indsp);

    // 4) gathers
    gather_kernel<<<dim3((BB*CC*SS)/256), 256, 0, stream>>>(xyz, feats, o1, indsp, o2, o4, o5);

    // 5) second fused conv stack -> vp_xyz
    gemm_fused<<<dim3(SS/TN, BB), 256, 0, stream>>>(
        o4, SS, SS, c1_w, c1_b, bn_g, bn_b, bn_m, bn_v, c2_w, c2_b,
        1, nullptr, nullptr, nullptr, o6);

    // 6) view argmax + rotation matrices
    view_rot_kernel<<<dim3((BB*SS)/256), 256, 0, stream>>>(o6, o7, o8);
}

// Round 2
// 2196.424 us; speedup vs baseline: 1.4522x; 1.4522x over previous
//
#include <hip/hip_runtime.h>
#include <hip/hip_bf16.h>
#include <math.h>

static constexpr int BB = 4;
static constexpr int NN = 20000;
static constexpr int CC = 256;
static constexpr int SS = 1024;   // NUM_SAMPLE
static constexpr int NV = 300;    // NUM_VIEW

// output offsets (floats) in d_out, concatenated in reference return order
static constexpr size_t O0 = 0;                     // objectness (B,2,N)
static constexpr size_t O1 = O0 + (size_t)BB*2*NN;  // graspness (B,N)
static constexpr size_t O2 = O1 + (size_t)BB*NN;    // graspable_xyz (B,S,3)
static constexpr size_t O3 = O2 + (size_t)BB*SS*3;  // graspable_inds (B,S) as float
static constexpr size_t O4 = O3 + (size_t)BB*SS;    // graspable_features (B,C,S)
static constexpr size_t O5 = O4 + (size_t)BB*CC*SS; // fp2_graspness (B,S)
static constexpr size_t O6 = O5 + (size_t)BB*SS;    // vp_xyz (B,S,3)
static constexpr size_t O7 = O6 + (size_t)BB*SS*3;  // top_view_inds (B,S) as float
static constexpr size_t O8 = O7 + (size_t)BB*SS;    // vp_rot (B,S,3,3)

// ---------------------------------------------------------------------------
// Fused GEMM: out3ch = W2(3x256) @ relu(bn(W1(256x256) @ X + b1)) + b2
// mode 0: write objectness/graspness/mask   mode 1: write vp_xyz (B,S,3)
// ---------------------------------------------------------------------------
static constexpr int TN = 64;     // columns per block
static constexpr int KC = 32;     // k-chunk
static constexpr int SW_LD = 260; // padded LDS row for sW[k][m]
static constexpr int PS_LD = 68;  // padded LDS row for psum

__global__ __launch_bounds__(256, 2) void gemm_fused(
    const float* __restrict__ X, int ncols, int cstride,
    const float* __restrict__ W1, const float* __restrict__ B1v,
    const float* __restrict__ Gv, const float* __restrict__ BEv,
    const float* __restrict__ Mv, const float* __restrict__ Vv,
    const float* __restrict__ W2, const float* __restrict__ B2v,
    int mode, float* __restrict__ o0, float* __restrict__ o1,
    unsigned char* __restrict__ maskp, float* __restrict__ vp)
{
    __shared__ alignas(16) char smem_raw[KC*SW_LD*4 + KC*TN*4]; // 41472 B (phase2 aliases)
    float* sW   = (float*)smem_raw;                       // [KC][SW_LD]
    float* sF   = (float*)(smem_raw + KC*SW_LD*4);        // [KC][TN]
    float* psum = (float*)smem_raw;                       // [3][32][PS_LD] = 26112 B
    float* gout = (float*)(smem_raw + 3*32*PS_LD*4);      // [3][64]

    const int t  = threadIdx.x;
    const int b  = blockIdx.y;
    const int n0 = blockIdx.x * TN;
    const int tm = t & 31;   // 32 groups along M (8 rows each)
    const int tn = t >> 5;   // 8 groups along N (8 cols each)

    const float* Xb = X + (size_t)b * CC * cstride;

    float acc[8][8];
#pragma unroll
    for (int i = 0; i < 8; ++i)
#pragma unroll
        for (int j = 0; j < 8; ++j) acc[i][j] = 0.f;

    for (int k0 = 0; k0 < CC; k0 += KC) {
        // stage W1 tile (256 x KC), transposed into sW[k][m]
#pragma unroll
        for (int r = 0; r < (CC*KC)/256; ++r) {
            int idx = r*256 + t;
            int m  = idx >> 5;
            int kk = idx & 31;
            sW[kk*SW_LD + m] = W1[m*CC + k0 + kk];
        }
        // stage X tile (KC x 64)
#pragma unroll
        for (int r = 0; r < (KC*TN)/256; ++r) {
            int idx = r*256 + t;
            int kk = idx >> 6;
            int j  = idx & 63;
            int col = n0 + j;
            float v = 0.f;
            if (col < ncols) v = Xb[(size_t)(k0+kk)*cstride + col];
            sF[kk*TN + j] = v;
        }
        __syncthreads();
#pragma unroll 8
        for (int kk = 0; kk < KC; ++kk) {
            const float4 a0 = *(const float4*)(sW + kk*SW_LD + tm*8);
            const float4 a1 = *(const float4*)(sW + kk*SW_LD + tm*8 + 4);
            const float4 f0 = *(const float4*)(sF + kk*TN + tn*8);
            const float4 f1 = *(const float4*)(sF + kk*TN + tn*8 + 4);
            float av[8] = {a0.x,a0.y,a0.z,a0.w,a1.x,a1.y,a1.z,a1.w};
            float bv[8] = {f0.x,f0.y,f0.z,f0.w,f1.x,f1.y,f1.z,f1.w};
#pragma unroll
            for (int i = 0; i < 8; ++i)
#pragma unroll
                for (int j = 0; j < 8; ++j)
                    acc[i][j] = fmaf(av[i], bv[j], acc[i][j]);
        }
        __syncthreads();
    }

    // epilogue: bias + bn + relu in registers, partial W2 contraction
    float part[3][8];
#pragma unroll
    for (int r = 0; r < 3; ++r)
#pragma unroll
        for (int j = 0; j < 8; ++j) part[r][j] = 0.f;

#pragma unroll
    for (int i = 0; i < 8; ++i) {
        int m = tm*8 + i;
        float scale = __fdiv_rn(Gv[m], __fsqrt_rn(__fadd_rn(Vv[m], 1e-5f)));
        float shift = __fsub_rn(BEv[m], __fmul_rn(Mv[m], scale));
        float w0 = W2[m], w1 = W2[CC + m], w2 = W2[2*CC + m];
        float b1m = B1v[m];
#pragma unroll
        for (int j = 0; j < 8; ++j) {
            float x = __fadd_rn(acc[i][j], b1m);
            float y = __fadd_rn(__fmul_rn(x, scale), shift);
            float h = y > 0.f ? y : 0.f;
            part[0][j] = fmaf(w0, h, part[0][j]);
            part[1][j] = fmaf(w1, h, part[1][j]);
            part[2][j] = fmaf(w2, h, part[2][j]);
        }
    }
#pragma unroll
    for (int r = 0; r < 3; ++r) {
        float4 p0 = {part[r][0], part[r][1], part[r][2], part[r][3]};
        float4 p1 = {part[r][4], part[r][5], part[r][6], part[r][7]};
        *(float4*)(psum + (r*32 + tm)*PS_LD + tn*8)     = p0;
        *(float4*)(psum + (r*32 + tm)*PS_LD + tn*8 + 4) = p1;
    }
    __syncthreads();
    if (t < 192) {
        int r = t >> 6, col = t & 63;
        float s = 0.f;
#pragma unroll
        for (int w = 0; w < 32; ++w) s = __fadd_rn(s, psum[(r*32 + w)*PS_LD + col]);
        float tot = __fadd_rn(s, B2v[r]);
        if (mode == 0) {
            gout[r*64 + col] = tot;
        } else {
            vp[((size_t)b*SS + n0 + col)*3 + r] = tot;
        }
    }
    if (mode == 0) {
        __syncthreads();
        if (t < 64) {
            int n = n0 + t;
            if (n < ncols) {
                float v0 = gout[t], v1 = gout[64 + t], v2 = gout[128 + t];
                o0[(size_t)b*2*ncols + n]         = v0;
                o0[(size_t)b*2*ncols + ncols + n] = v1;
                o1[(size_t)b*ncols + n]           = v2;
                maskp[(size_t)b*ncols + n] = (v2 > 0.1f && v1 > v0) ? 1 : 0;
            }
        }
    }
}

// ---------------------------------------------------------------------------
// Order-preserving stream compaction of masked-in candidates
// ---------------------------------------------------------------------------
__global__ __launch_bounds__(256) void compact_kernel(
    const unsigned char* __restrict__ maskp, const float* __restrict__ xyz,
    int* __restrict__ cntp, int* __restrict__ corig,
    float* __restrict__ cx, float* __restrict__ cy, float* __restrict__ cz)
{
    const int b = blockIdx.x;
    const int t = threadIdx.x;
    __shared__ int wsum[4];
    __shared__ int running;
    if (t == 0) running = 0;
    __syncthreads();
    const unsigned char* mb = maskp + (size_t)b*NN;
    const size_t bofs = (size_t)b*NN;
    for (int base = 0; base < NN; base += 256) {
        int i = base + t;
        int m = (i < NN) ? (int)mb[i] : 0;
        unsigned long long bal = __ballot(m != 0);
        int lane = t & 63, w = t >> 6;
        int pre = __popcll(bal & ((1ull << lane) - 1ull));
        if (lane == 0) wsum[w] = __popcll(bal);
        __syncthreads();
        int offs = running;
        for (int ww = 0; ww < w; ++ww) offs += wsum[ww];
        if (m) {
            int pos = offs + pre;
            corig[bofs + pos] = i;
            cx[bofs + pos] = xyz[(bofs + i)*3 + 0];
            cy[bofs + pos] = xyz[(bofs + i)*3 + 1];
            cz[bofs + pos] = xyz[(bofs + i)*3 + 2];
        }
        __syncthreads();
        if (t == 0) running += wsum[0] + wsum[1] + wsum[2] + wsum[3];
    }
    __syncthreads();
    if (t == 0) cntp[b] = running;
}

// ---------------------------------------------------------------------------
// Masked FPS over compacted candidates.
// Path A (cnt <= 5120): candidates in VGPRs (compile-time unrolled, padded
//   with D=-inf so invalid slots never win), xyz mirrored in LDS for the
//   per-iteration winner broadcast. Winner history kept in LDS; corig gather
//   and output stores happen in ONE parallel pass after the serial loop so
//   no global ops sit on the 1023-iteration critical path.
// Path B (cnt > 5120): D in LDS, xyz streamed from L2. Correctness fallback.
// ---------------------------------------------------------------------------
static constexpr int FPS_T = 512;
static constexpr int KA    = 10;          // register slots per thread (path A)
static constexpr int CAPA  = FPS_T * KA;  // 5120

__global__ __launch_bounds__(FPS_T, 1) void fps_kernel(
    const int* __restrict__ cntp, const int* __restrict__ corig,
    const float* __restrict__ cx, const float* __restrict__ cy, const float* __restrict__ cz,
    float* __restrict__ o3, int* __restrict__ oi)
{
    const int b = blockIdx.x;
    const int t = threadIdx.x;
    const int cnt = cntp[b];
    const size_t bofs = (size_t)b*NN;
    float* o3b = o3 + (size_t)b*SS;
    int*   oib = oi + (size_t)b*SS;

    if (cnt <= 0) {
        for (int s = t; s < SS; s += FPS_T) { o3b[s] = 0.f; oib[s] = 0; }
        return;
    }

    __shared__ float sdata[NN];        // path A: sx/sy/sz (3*5120); path B: D[cnt]
    __shared__ float swv[2][8];
    __shared__ int   swi[2][8];
    __shared__ int   whist[SS];

    const int wave = t >> 6, lane = t & 63;

    if (t == 0) whist[0] = 0;          // first selected = compacted index 0

    if (cnt <= CAPA) {
        // ---------------- Path A: registers + LDS xyz mirror ----------------
        float* sx = sdata;
        float* sy = sdata + CAPA;
        float* sz = sdata + 2*CAPA;
        for (int g = t; g < cnt; g += FPS_T) {
            sx[g] = cx[bofs + g];
            sy[g] = cy[bofs + g];
            sz[g] = cz[bofs + g];
        }

        float X[KA], Y[KA], Z[KA], D[KA];
#pragma unroll
        for (int j = 0; j < KA; ++j) {
            int g = t + (j << 9);
            bool v = g < cnt;
            X[j] = v ? cx[bofs + g] : 0.f;
            Y[j] = v ? cy[bofs + g] : 0.f;
            Z[j] = v ? cz[bofs + g] : 0.f;
            D[j] = v ? 1e10f : -INFINITY;
        }

        float px = cx[bofs], py = cy[bofs], pz = cz[bofs];

        for (int it = 1; it < SS; ++it) {
            float bv = -INFINITY; int bi = 0x7fffffff;
#pragma unroll
            for (int j = 0; j < KA; ++j) {
                float dx = __fsub_rn(X[j], px);
                float dy = __fsub_rn(Y[j], py);
                float dz = __fsub_rn(Z[j], pz);
                float d  = __fadd_rn(__fadd_rn(__fmul_rn(dx,dx), __fmul_rn(dy,dy)), __fmul_rn(dz,dz));
                float dn = fminf(D[j], d);
                D[j] = dn;
                if (dn > bv) { bv = dn; bi = t + (j << 9); }
            }
#pragma unroll
            for (int off = 32; off > 0; off >>= 1) {
                float ov  = __shfl_xor(bv, off, 64);
                int   oix = __shfl_xor(bi, off, 64);
                if (ov > bv || (ov == bv && oix < bi)) { bv = ov; bi = oix; }
            }
            int par = it & 1;
            if (lane == 0) { swv[par][wave] = bv; swi[par][wave] = bi; }
            __syncthreads();
            float wv = swv[par][0]; int wi = swi[par][0];
#pragma unroll
            for (int w = 1; w < 8; ++w) {
                float v2 = swv[par][w]; int i2 = swi[par][w];
                if (v2 > wv || (v2 == wv && i2 < wi)) { wv = v2; wi = i2; }
            }
            px = sx[wi]; py = sy[wi]; pz = sz[wi];
            if (t == 0) whist[it] = wi;
        }
    } else {
        // ---------------- Path B: LDS distances, streamed xyz ---------------
        float* Dl = sdata;
        for (int g = t; g < cnt; g += FPS_T) Dl[g] = 1e10f;
        __syncthreads();

        float px = cx[bofs], py = cy[bofs], pz = cz[bofs];

        for (int it = 1; it < SS; ++it) {
            float bv = -INFINITY; int bi = 0x7fffffff;
            for (int g = t; g < cnt; g += FPS_T) {
                float dx = __fsub_rn(cx[bofs + g], px);
                float dy = __fsub_rn(cy[bofs + g], py);
                float dz = __fsub_rn(cz[bofs + g], pz);
                float d  = __fadd_rn(__fadd_rn(__fmul_rn(dx,dx), __fmul_rn(dy,dy)), __fmul_rn(dz,dz));
                float dn = fminf(Dl[g], d);
                Dl[g] = dn;
                if (dn > bv) { bv = dn; bi = g; }
            }
#pragma unroll
            for (int off = 32; off > 0; off >>= 1) {
                float ov  = __shfl_xor(bv, off, 64);
                int   oix = __shfl_xor(bi, off, 64);
                if (ov > bv || (ov == bv && oix < bi)) { bv = ov; bi = oix; }
            }
            int par = it & 1;
            if (lane == 0) { swv[par][wave] = bv; swi[par][wave] = bi; }
            __syncthreads();
            float wv = swv[par][0]; int wi = swi[par][0];
#pragma unroll
            for (int w = 1; w < 8; ++w) {
                float v2 = swv[par][w]; int i2 = swi[par][w];
                if (v2 > wv || (v2 == wv && i2 < wi)) { wv = v2; wi = i2; }
            }
            px = cx[bofs + wi]; py = cy[bofs + wi]; pz = cz[bofs + wi];
            if (t == 0) whist[it] = wi;
        }
    }

    __syncthreads();   // make whist[] fully visible
    for (int s = t; s < SS; s += FPS_T) {
        int wi  = whist[s];
        int org = corig[bofs + wi];
        oib[s] = org;
        o3b[s] = (float)org;
    }
}

// ---------------------------------------------------------------------------
// Gathers: graspable_xyz, graspable_features, fp2_graspness
// ---------------------------------------------------------------------------
__global__ __launch_bounds__(256) void gather_kernel(
    const float* __restrict__ xyz, const float* __restrict__ feats,
    const float* __restrict__ grasp, const int* __restrict__ inds,
    float* __restrict__ o2, float* __restrict__ o4, float* __restrict__ o5)
{
    int e = blockIdx.x * 256 + threadIdx.x;   // B*C*S = 1,048,576 exactly
    int b = e >> 18;
    int r = e & ((1 << 18) - 1);
    int c = r >> 10;
    int s = r & 1023;
    int idx = inds[(b << 10) + s];
    o4[e] = feats[((size_t)b*CC + c)*NN + idx];
    if (c == 0) {
        o5[(b << 10) + s] = grasp[(size_t)b*NN + idx];
        size_t src = ((size_t)b*NN + idx)*3;
        size_t dst = ((size_t)(b << 10) + s)*3;
        o2[dst + 0] = xyz[src + 0];
        o2[dst + 1] = xyz[src + 1];
        o2[dst + 2] = xyz[src + 2];
    }
}

// ---------------------------------------------------------------------------
// top_view argmax + vp_rot
// ---------------------------------------------------------------------------
__global__ __launch_bounds__(256) void view_rot_kernel(
    const float* __restrict__ vp, float* __restrict__ o7, float* __restrict__ o8)
{
    __shared__ float tvx[NV], tvy[NV], tvz[NV];
    int t = threadIdx.x;
    for (int i = t; i < NV; i += 256) {
        double phi = (sqrt(5.0) - 1.0) * 0.5;
        double zd  = (2.0*(double)i + 1.0)/300.0 - 1.0;
        double rr  = sqrt(fmax(1.0 - zd*zd, 0.0));
        double ang = 2.0 * 3.14159265358979323846 * (double)i * phi;
        float fx = (float)(rr * cos(ang));
        float fy = (float)(rr * sin(ang));
        float fz = (float)zd;
        float nr = __fsqrt_rn(__fadd_rn(__fadd_rn(__fmul_rn(fx,fx), __fmul_rn(fy,fy)), __fmul_rn(fz,fz)));
        float dn = fmaxf(nr, 1e-8f);
        tvx[i] = __fdiv_rn(fx, dn);
        tvy[i] = __fdiv_rn(fy, dn);
        tvz[i] = __fdiv_rn(fz, dn);
    }
    __syncthreads();
    int sg = blockIdx.x * 256 + t;   // 0..4095
    float vx = vp[(size_t)sg*3 + 0];
    float vy = vp[(size_t)sg*3 + 1];
    float vz = vp[(size_t)sg*3 + 2];

    float nr = __fsqrt_rn(__fadd_rn(__fadd_rn(__fmul_rn(vx,vx), __fmul_rn(vy,vy)), __fmul_rn(vz,vz)));
    float dn = fmaxf(nr, 1e-8f);
    float ux = __fdiv_rn(vx, dn), uy = __fdiv_rn(vy, dn), uz = __fdiv_rn(vz, dn);
    float best = -INFINITY; int bidx = 0;
    for (int v = 0; v < NV; ++v) {
        float c = __fadd_rn(__fadd_rn(__fmul_rn(ux, tvx[v]), __fmul_rn(uy, tvy[v])), __fmul_rn(uz, tvz[v]));
        if (c > best) { best = c; bidx = v; }
    }
    o7[sg] = (float)bidx;

    // vp_rot: towards = -vp
    float axx = -vx, axy = -vy, axz = -vz;
    float ayx = vy, ayy = -vx, ayz = 0.f;          // ay = [-ax.y, ax.x, 0]
    float s2 = __fadd_rn(__fadd_rn(__fmul_rn(ayx,ayx), __fmul_rn(ayy,ayy)), 0.f);
    if (s2 == 0.f) { ayx = 0.f; ayy = 1.f; ayz = 0.f; }
    float an = __fsqrt_rn(__fadd_rn(__fadd_rn(__fmul_rn(axx,axx), __fmul_rn(axy,axy)), __fmul_rn(axz,axz)));
    float nx0 = __fdiv_rn(axx, an), nx1 = __fdiv_rn(axy, an), nx2 = __fdiv_rn(axz, an);
    float bn2 = __fsqrt_rn(__fadd_rn(__fadd_rn(__fmul_rn(ayx,ayx), __fmul_rn(ayy,ayy)), __fmul_rn(ayz,ayz)));
    float ny0 = __fdiv_rn(ayx, bn2), ny1 = __fdiv_rn(ayy, bn2), ny2 = __fdiv_rn(ayz, bn2);
    float nz0 = __fsub_rn(__fmul_rn(nx1, ny2), __fmul_rn(nx2, ny1));
    float nz1 = __fsub_rn(__fmul_rn(nx2, ny0), __fmul_rn(nx0, ny2));
    float nz2 = __fsub_rn(__fmul_rn(nx0, ny1), __fmul_rn(nx1, ny0));
    size_t o = (size_t)sg * 9;   // rows = (nx_i, ny_i, nz_i)
    o8[o+0] = nx0; o8[o+1] = ny0; o8[o+2] = nz0;
    o8[o+3] = nx1; o8[o+4] = ny1; o8[o+5] = nz1;
    o8[o+6] = nx2; o8[o+7] = ny2; o8[o+8] = nz2;
}

// ---------------------------------------------------------------------------
extern "C" void kernel_launch(void* const* d_in, const int* in_sizes, int n_in,
                              void* d_out, int out_size, void* d_ws, size_t ws_size,
                              hipStream_t stream) {
    const float* xyz   = (const float*)d_in[0];
    const float* feats = (const float*)d_in[1];
    const float* gh_w1 = (const float*)d_in[2];
    const float* gh_b1 = (const float*)d_in[3];
    const float* gh_g  = (const float*)d_in[4];
    const float* gh_be = (const float*)d_in[5];
    const float* gh_m  = (const float*)d_in[6];
    const float* gh_v  = (const float*)d_in[7];
    const float* gh_w2 = (const float*)d_in[8];
    const float* gh_b2 = (const float*)d_in[9];
    const float* c1_w  = (const float*)d_in[10];
    const float* c1_b  = (const float*)d_in[11];
    const float* bn_g  = (const float*)d_in[12];
    const float* bn_b  = (const float*)d_in[13];
    const float* bn_m  = (const float*)d_in[14];
    const float* bn_v  = (const float*)d_in[15];
    const float* c2_w  = (const float*)d_in[16];
    const float* c2_b  = (const float*)d_in[17];

    float* out = (float*)d_out;
    float* o0 = out + O0;
    float* o1 = out + O1;
    float* o2 = out + O2;
    float* o3 = out + O3;
    float* o4 = out + O4;
    float* o5 = out + O5;
    float* o6 = out + O6;
    float* o7 = out + O7;
    float* o8 = out + O8;

    char* ws = (char*)d_ws;
    size_t off = 0;
    auto take = [&](size_t bytes) -> char* {
        char* p = ws + off;
        off = (off + bytes + 255) & ~(size_t)255;
        return p;
    };
    unsigned char* maskp = (unsigned char*)take((size_t)BB*NN);
    int*   cntp  = (int*)take((size_t)BB*4);
    int*   corig = (int*)take((size_t)BB*NN*4);
    float* cx    = (float*)take((size_t)BB*NN*4);
    float* cy    = (float*)take((size_t)BB*NN*4);
    float* cz    = (float*)take((size_t)BB*NN*4);
    int*   indsp = (int*)take((size_t)BB*SS*4);

    // 1) fused conv+bn+relu+conv over all N points
    gemm_fused<<<dim3((NN + TN - 1)/TN, BB), 256, 0, stream>>>(
        feats, NN, NN, gh_w1, gh_b1, gh_g, gh_be, gh_m, gh_v, gh_w2, gh_b2,
        0, o0, o1, maskp, nullptr);

    // 2) compact masked-in candidates (order-preserving)
    compact_kernel<<<dim3(BB), 256, 0, stream>>>(maskp, xyz, cntp, corig, cx, cy, cz);

    // 3) sequential FPS over candidates
    fps_kernel<<<dim3(BB), FPS_T, 0, stream>>>(cntp, corig, cx, cy, cz, o3, indsp);

    // 4) gathers
    gather_kernel<<<dim3((BB*CC*SS)/256), 256, 0, stream>>>(xyz, feats, o1, indsp, o2, o4, o5);

    // 5) second fused conv stack -> vp_xyz
    gemm_fused<<<dim3(SS/TN, BB), 256, 0, stream>>>(
        o4, SS, SS, c1_w, c1_b, bn_g, bn_b, bn_m, bn_v, c2_w, c2_b,
        1, nullptr, nullptr, nullptr, o6);

    // 6) view argmax + rotation matrices
    view_rot_kernel<<<dim3((BB*SS)/256), 256, 0, stream>>>(o6, o7, o8);
}

// Round 3
// 1669.292 us; speedup vs baseline: 1.9108x; 1.3158x over previous
//
#include <hip/hip_runtime.h>
#include <hip/hip_bf16.h>
#include <math.h>

static constexpr int BB = 4;
static constexpr int NN = 20000;
static constexpr int CC = 256;
static constexpr int SS = 1024;   // NUM_SAMPLE
static constexpr int NV = 300;    // NUM_VIEW

// output offsets (floats) in d_out, concatenated in reference return order
static constexpr size_t O0 = 0;                     // objectness (B,2,N)
static constexpr size_t O1 = O0 + (size_t)BB*2*NN;  // graspness (B,N)
static constexpr size_t O2 = O1 + (size_t)BB*NN;    // graspable_xyz (B,S,3)
static constexpr size_t O3 = O2 + (size_t)BB*SS*3;  // graspable_inds (B,S) as float
static constexpr size_t O4 = O3 + (size_t)BB*SS;    // graspable_features (B,C,S)
static constexpr size_t O5 = O4 + (size_t)BB*CC*SS; // fp2_graspness (B,S)
static constexpr size_t O6 = O5 + (size_t)BB*SS;    // vp_xyz (B,S,3)
static constexpr size_t O7 = O6 + (size_t)BB*SS*3;  // top_view_inds (B,S) as float
static constexpr size_t O8 = O7 + (size_t)BB*SS;    // vp_rot (B,S,3,3)

// ---------------------------------------------------------------------------
// Fused GEMM: out3ch = W2(3x256) @ relu(bn(W1(256x256) @ X + b1)) + b2
// mode 0: write objectness/graspness/mask   mode 1: write vp_xyz (B,S,3)
// ---------------------------------------------------------------------------
static constexpr int TN = 64;     // columns per block
static constexpr int KC = 32;     // k-chunk
static constexpr int SW_LD = 260; // padded LDS row for sW[k][m]
static constexpr int PS_LD = 68;  // padded LDS row for psum

__global__ __launch_bounds__(256, 2) void gemm_fused(
    const float* __restrict__ X, int ncols, int cstride,
    const float* __restrict__ W1, const float* __restrict__ B1v,
    const float* __restrict__ Gv, const float* __restrict__ BEv,
    const float* __restrict__ Mv, const float* __restrict__ Vv,
    const float* __restrict__ W2, const float* __restrict__ B2v,
    int mode, float* __restrict__ o0, float* __restrict__ o1,
    unsigned char* __restrict__ maskp, float* __restrict__ vp)
{
    __shared__ alignas(16) char smem_raw[KC*SW_LD*4 + KC*TN*4]; // 41472 B (phase2 aliases)
    float* sW   = (float*)smem_raw;                       // [KC][SW_LD]
    float* sF   = (float*)(smem_raw + KC*SW_LD*4);        // [KC][TN]
    float* psum = (float*)smem_raw;                       // [3][32][PS_LD] = 26112 B
    float* gout = (float*)(smem_raw + 3*32*PS_LD*4);      // [3][64]

    const int t  = threadIdx.x;
    const int b  = blockIdx.y;
    const int n0 = blockIdx.x * TN;
    const int tm = t & 31;   // 32 groups along M (8 rows each)
    const int tn = t >> 5;   // 8 groups along N (8 cols each)

    const float* Xb = X + (size_t)b * CC * cstride;

    float acc[8][8];
#pragma unroll
    for (int i = 0; i < 8; ++i)
#pragma unroll
        for (int j = 0; j < 8; ++j) acc[i][j] = 0.f;

    for (int k0 = 0; k0 < CC; k0 += KC) {
        // stage W1 tile (256 x KC), transposed into sW[k][m]
#pragma unroll
        for (int r = 0; r < (CC*KC)/256; ++r) {
            int idx = r*256 + t;
            int m  = idx >> 5;
            int kk = idx & 31;
            sW[kk*SW_LD + m] = W1[m*CC + k0 + kk];
        }
        // stage X tile (KC x 64)
#pragma unroll
        for (int r = 0; r < (KC*TN)/256; ++r) {
            int idx = r*256 + t;
            int kk = idx >> 6;
            int j  = idx & 63;
            int col = n0 + j;
            float v = 0.f;
            if (col < ncols) v = Xb[(size_t)(k0+kk)*cstride + col];
            sF[kk*TN + j] = v;
        }
        __syncthreads();
#pragma unroll 8
        for (int kk = 0; kk < KC; ++kk) {
            const float4 a0 = *(const float4*)(sW + kk*SW_LD + tm*8);
            const float4 a1 = *(const float4*)(sW + kk*SW_LD + tm*8 + 4);
            const float4 f0 = *(const float4*)(sF + kk*TN + tn*8);
            const float4 f1 = *(const float4*)(sF + kk*TN + tn*8 + 4);
            float av[8] = {a0.x,a0.y,a0.z,a0.w,a1.x,a1.y,a1.z,a1.w};
            float bv[8] = {f0.x,f0.y,f0.z,f0.w,f1.x,f1.y,f1.z,f1.w};
#pragma unroll
            for (int i = 0; i < 8; ++i)
#pragma unroll
                for (int j = 0; j < 8; ++j)
                    acc[i][j] = fmaf(av[i], bv[j], acc[i][j]);
        }
        __syncthreads();
    }

    // epilogue: bias + bn + relu in registers, partial W2 contraction
    float part[3][8];
#pragma unroll
    for (int r = 0; r < 3; ++r)
#pragma unroll
        for (int j = 0; j < 8; ++j) part[r][j] = 0.f;

#pragma unroll
    for (int i = 0; i < 8; ++i) {
        int m = tm*8 + i;
        float scale = __fdiv_rn(Gv[m], __fsqrt_rn(__fadd_rn(Vv[m], 1e-5f)));
        float shift = __fsub_rn(BEv[m], __fmul_rn(Mv[m], scale));
        float w0 = W2[m], w1 = W2[CC + m], w2 = W2[2*CC + m];
        float b1m = B1v[m];
#pragma unroll
        for (int j = 0; j < 8; ++j) {
            float x = __fadd_rn(acc[i][j], b1m);
            float y = __fadd_rn(__fmul_rn(x, scale), shift);
            float h = y > 0.f ? y : 0.f;
            part[0][j] = fmaf(w0, h, part[0][j]);
            part[1][j] = fmaf(w1, h, part[1][j]);
            part[2][j] = fmaf(w2, h, part[2][j]);
        }
    }
#pragma unroll
    for (int r = 0; r < 3; ++r) {
        float4 p0 = {part[r][0], part[r][1], part[r][2], part[r][3]};
        float4 p1 = {part[r][4], part[r][5], part[r][6], part[r][7]};
        *(float4*)(psum + (r*32 + tm)*PS_LD + tn*8)     = p0;
        *(float4*)(psum + (r*32 + tm)*PS_LD + tn*8 + 4) = p1;
    }
    __syncthreads();
    if (t < 192) {
        int r = t >> 6, col = t & 63;
        float s = 0.f;
#pragma unroll
        for (int w = 0; w < 32; ++w) s = __fadd_rn(s, psum[(r*32 + w)*PS_LD + col]);
        float tot = __fadd_rn(s, B2v[r]);
        if (mode == 0) {
            gout[r*64 + col] = tot;
        } else {
            vp[((size_t)b*SS + n0 + col)*3 + r] = tot;
        }
    }
    if (mode == 0) {
        __syncthreads();
        if (t < 64) {
            int n = n0 + t;
            if (n < ncols) {
                float v0 = gout[t], v1 = gout[64 + t], v2 = gout[128 + t];
                o0[(size_t)b*2*ncols + n]         = v0;
                o0[(size_t)b*2*ncols + ncols + n] = v1;
                o1[(size_t)b*ncols + n]           = v2;
                maskp[(size_t)b*ncols + n] = (v2 > 0.1f && v1 > v0) ? 1 : 0;
            }
        }
    }
}

// ---------------------------------------------------------------------------
// Order-preserving stream compaction of masked-in candidates
// ---------------------------------------------------------------------------
__global__ __launch_bounds__(256) void compact_kernel(
    const unsigned char* __restrict__ maskp, const float* __restrict__ xyz,
    int* __restrict__ cntp, int* __restrict__ corig,
    float* __restrict__ cx, float* __restrict__ cy, float* __restrict__ cz)
{
    const int b = blockIdx.x;
    const int t = threadIdx.x;
    __shared__ int wsum[4];
    __shared__ int running;
    if (t == 0) running = 0;
    __syncthreads();
    const unsigned char* mb = maskp + (size_t)b*NN;
    const size_t bofs = (size_t)b*NN;
    for (int base = 0; base < NN; base += 256) {
        int i = base + t;
        int m = (i < NN) ? (int)mb[i] : 0;
        unsigned long long bal = __ballot(m != 0);
        int lane = t & 63, w = t >> 6;
        int pre = __popcll(bal & ((1ull << lane) - 1ull));
        if (lane == 0) wsum[w] = __popcll(bal);
        __syncthreads();
        int offs = running;
        for (int ww = 0; ww < w; ++ww) offs += wsum[ww];
        if (m) {
            int pos = offs + pre;
            corig[bofs + pos] = i;
            cx[bofs + pos] = xyz[(bofs + i)*3 + 0];
            cy[bofs + pos] = xyz[(bofs + i)*3 + 1];
            cz[bofs + pos] = xyz[(bofs + i)*3 + 2];
        }
        __syncthreads();
        if (t == 0) running += wsum[0] + wsum[1] + wsum[2] + wsum[3];
    }
    __syncthreads();
    if (t == 0) cntp[b] = running;
}

// ---------------------------------------------------------------------------
// Masked FPS. Grid = 256 blocks: blocks [0,BB) run the serial FPS for one
// batch each (LDS forces 1 block/CU so all 256 blocks are co-resident);
// blocks [BB,256) run a bounded FMA spin polling a device-scope done flag —
// they keep GPU busy% high so the DPM governor holds max SCLK during the
// latency-bound FPS window (4/256 CUs active otherwise -> clock sag).
//
// Wave argmax uses DPP (VALU-only, no ds_permute/waitcnt chain):
//   row_shr 1/2/4/8 + row_bcast15 + row_bcast31 -> lane 63 holds wave best.
// Cross-wave: packed u64 keys (bits(d)<<32 | (0xFFFFFFFF-idx)) -> one
// ds_read_b128 pair + 7 u64 compares. Tie -> lowest index, matching np.
// ---------------------------------------------------------------------------
static constexpr int FPS_T = 512;
static constexpr int KA    = 10;          // register slots per thread (path A)
static constexpr int CAPA  = FPS_T * KA;  // 5120

template<int CTRL>
__device__ __forceinline__ void dpp_amax_step(float& v, int& i) {
    int ovb = __builtin_amdgcn_update_dpp(0xFF800000, __float_as_int(v), CTRL, 0xf, 0xf, false);
    int oi  = __builtin_amdgcn_update_dpp(0x7FFFFFFF, i, CTRL, 0xf, 0xf, false);
    float ov = __int_as_float(ovb);
    bool better = (ov > v) || (ov == v && oi < i);
    v = better ? ov : v;
    i = better ? oi : i;
}

__device__ __forceinline__ void wave_amax_dpp(float& v, int& i) {
    dpp_amax_step<0x111>(v, i);  // row_shr:1
    dpp_amax_step<0x112>(v, i);  // row_shr:2
    dpp_amax_step<0x114>(v, i);  // row_shr:4
    dpp_amax_step<0x118>(v, i);  // row_shr:8
    dpp_amax_step<0x142>(v, i);  // row_bcast:15
    dpp_amax_step<0x143>(v, i);  // row_bcast:31  -> lane 63 has wave argmax
}

__device__ __forceinline__ unsigned long long pack_key(float v, int i) {
    if (v == -INFINITY) return 0ull;   // wave had no valid slot
    return (((unsigned long long)__float_as_uint(v)) << 32)
         | (unsigned long long)(0xFFFFFFFFu - (unsigned)i);
}

__global__ __launch_bounds__(FPS_T, 1) void fps_kernel(
    const int* __restrict__ cntp, const int* __restrict__ corig,
    const float* __restrict__ cx, const float* __restrict__ cy, const float* __restrict__ cz,
    float* __restrict__ o3, int* __restrict__ oi, int* __restrict__ donep)
{
    const int t = threadIdx.x;

    __shared__ alignas(16) float sxyz[CAPA*4];                // 80 KiB (path B aliases D[] here)
    __shared__ alignas(16) unsigned long long swk[2][8];
    __shared__ int whist[SS];
    __shared__ int sdone;

    if (blockIdx.x >= BB) {
        // ---------------- clock-warm block ----------------
        if (t == 0) sdone = 0;
        __syncthreads();
        float a = 1.0f + (float)t * 1e-6f, bm = 1.0000001f, c = 0.f;
        for (int iter = 0; iter < 60000; ++iter) {
#pragma unroll
            for (int u = 0; u < 32; ++u) c = fmaf(a, bm, c);
            if (t == 0 && (iter & 7) == 0) {
                if (__hip_atomic_load(donep, __ATOMIC_RELAXED, __HIP_MEMORY_SCOPE_AGENT) >= BB)
                    *(volatile int*)&sdone = 1;
            }
            if (*(volatile int*)&sdone) break;
        }
        if (t == 0) donep[4 + (blockIdx.x & 3)] = __float_as_int(c);  // keep c live (scratch)
        return;
    }

    const int b = blockIdx.x;
    const int cnt = cntp[b];
    const size_t bofs = (size_t)b*NN;
    float* o3b = o3 + (size_t)b*SS;
    int*   oib = oi + (size_t)b*SS;
    const int wave = t >> 6, lane = t & 63;

    if (cnt <= 0) {
        for (int s = t; s < SS; s += FPS_T) { o3b[s] = 0.f; oib[s] = 0; }
        if (t == 0) __hip_atomic_fetch_add(donep, 1, __ATOMIC_RELEASE, __HIP_MEMORY_SCOPE_AGENT);
        return;
    }

    if (t == 0) whist[0] = 0;          // first selected = compacted index 0

    if (cnt <= CAPA) {
        // ---------------- Path A: registers + packed LDS xyz mirror ----------------
        for (int g = t; g < cnt; g += FPS_T) {
            float4 w4 = { cx[bofs + g], cy[bofs + g], cz[bofs + g], 0.f };
            *(float4*)&sxyz[g*4] = w4;
        }

        float X[KA], Y[KA], Z[KA], D[KA];
#pragma unroll
        for (int j = 0; j < KA; ++j) {
            int g = t + (j << 9);
            bool v = g < cnt;
            X[j] = v ? cx[bofs + g] : 0.f;
            Y[j] = v ? cy[bofs + g] : 0.f;
            Z[j] = v ? cz[bofs + g] : 0.f;
            D[j] = v ? 1e10f : -INFINITY;
        }

        float px = cx[bofs], py = cy[bofs], pz = cz[bofs];

        for (int it = 1; it < SS; ++it) {
            float bv = -INFINITY; int bi = 0x7fffffff;
#pragma unroll
            for (int j = 0; j < KA; ++j) {
                float dx = __fsub_rn(X[j], px);
                float dy = __fsub_rn(Y[j], py);
                float dz = __fsub_rn(Z[j], pz);
                float d  = __fadd_rn(__fadd_rn(__fmul_rn(dx,dx), __fmul_rn(dy,dy)), __fmul_rn(dz,dz));
                float dn = fminf(D[j], d);
                D[j] = dn;
                if (dn > bv) { bv = dn; bi = t + (j << 9); }
            }
            wave_amax_dpp(bv, bi);
            int par = it & 1;
            if (lane == 63) swk[par][wave] = pack_key(bv, bi);
            __syncthreads();
            const ulonglong2* kp = (const ulonglong2*)&swk[par][0];
            ulonglong2 k0 = kp[0], k1 = kp[1], k2 = kp[2], k3 = kp[3];
            unsigned long long best = k0.x;
            if (k0.y > best) best = k0.y;
            if (k1.x > best) best = k1.x;
            if (k1.y > best) best = k1.y;
            if (k2.x > best) best = k2.x;
            if (k2.y > best) best = k2.y;
            if (k3.x > best) best = k3.x;
            if (k3.y > best) best = k3.y;
            int wi = (int)(0xFFFFFFFFu - (unsigned)(best & 0xFFFFFFFFull));
            float4 w4 = *(float4*)&sxyz[wi*4];
            px = w4.x; py = w4.y; pz = w4.z;
            if (t == 0) whist[it] = wi;
        }
    } else {
        // ---------------- Path B: LDS distances, streamed xyz (fallback) ---------------
        float* Dl = sxyz;
        for (int g = t; g < cnt; g += FPS_T) Dl[g] = 1e10f;
        __syncthreads();

        float px = cx[bofs], py = cy[bofs], pz = cz[bofs];

        for (int it = 1; it < SS; ++it) {
            float bv = -INFINITY; int bi = 0x7fffffff;
            for (int g = t; g < cnt; g += FPS_T) {
                float dx = __fsub_rn(cx[bofs + g], px);
                float dy = __fsub_rn(cy[bofs + g], py);
                float dz = __fsub_rn(cz[bofs + g], pz);
                float d  = __fadd_rn(__fadd_rn(__fmul_rn(dx,dx), __fmul_rn(dy,dy)), __fmul_rn(dz,dz));
                float dn = fminf(Dl[g], d);
                Dl[g] = dn;
                if (dn > bv) { bv = dn; bi = g; }
            }
            wave_amax_dpp(bv, bi);
            int par = it & 1;
            if (lane == 63) swk[par][wave] = pack_key(bv, bi);
            __syncthreads();
            const ulonglong2* kp = (const ulonglong2*)&swk[par][0];
            ulonglong2 k0 = kp[0], k1 = kp[1], k2 = kp[2], k3 = kp[3];
            unsigned long long best = k0.x;
            if (k0.y > best) best = k0.y;
            if (k1.x > best) best = k1.x;
            if (k1.y > best) best = k1.y;
            if (k2.x > best) best = k2.x;
            if (k2.y > best) best = k2.y;
            if (k3.x > best) best = k3.x;
            if (k3.y > best) best = k3.y;
            int wi = (int)(0xFFFFFFFFu - (unsigned)(best & 0xFFFFFFFFull));
            px = cx[bofs + wi]; py = cy[bofs + wi]; pz = cz[bofs + wi];
            if (t == 0) whist[it] = wi;
        }
    }

    __syncthreads();   // make whist[] fully visible
    for (int s = t; s < SS; s += FPS_T) {
        int wi  = whist[s];
        int org = corig[bofs + wi];
        oib[s] = org;
        o3b[s] = (float)org;
    }
    if (t == 0) __hip_atomic_fetch_add(donep, 1, __ATOMIC_RELEASE, __HIP_MEMORY_SCOPE_AGENT);
}

// ---------------------------------------------------------------------------
// Gathers: graspable_xyz, graspable_features, fp2_graspness
// ---------------------------------------------------------------------------
__global__ __launch_bounds__(256) void gather_kernel(
    const float* __restrict__ xyz, const float* __restrict__ feats,
    const float* __restrict__ grasp, const int* __restrict__ inds,
    float* __restrict__ o2, float* __restrict__ o4, float* __restrict__ o5)
{
    int e = blockIdx.x * 256 + threadIdx.x;   // B*C*S = 1,048,576 exactly
    int b = e >> 18;
    int r = e & ((1 << 18) - 1);
    int c = r >> 10;
    int s = r & 1023;
    int idx = inds[(b << 10) + s];
    o4[e] = feats[((size_t)b*CC + c)*NN + idx];
    if (c == 0) {
        o5[(b << 10) + s] = grasp[(size_t)b*NN + idx];
        size_t src = ((size_t)b*NN + idx)*3;
        size_t dst = ((size_t)(b << 10) + s)*3;
        o2[dst + 0] = xyz[src + 0];
        o2[dst + 1] = xyz[src + 1];
        o2[dst + 2] = xyz[src + 2];
    }
}

// ---------------------------------------------------------------------------
// top_view argmax + vp_rot
// ---------------------------------------------------------------------------
__global__ __launch_bounds__(256) void view_rot_kernel(
    const float* __restrict__ vp, float* __restrict__ o7, float* __restrict__ o8)
{
    __shared__ float tvx[NV], tvy[NV], tvz[NV];
    int t = threadIdx.x;
    for (int i = t; i < NV; i += 256) {
        double phi = (sqrt(5.0) - 1.0) * 0.5;
        double zd  = (2.0*(double)i + 1.0)/300.0 - 1.0;
        double rr  = sqrt(fmax(1.0 - zd*zd, 0.0));
        double ang = 2.0 * 3.14159265358979323846 * (double)i * phi;
        float fx = (float)(rr * cos(ang));
        float fy = (float)(rr * sin(ang));
        float fz = (float)zd;
        float nr = __fsqrt_rn(__fadd_rn(__fadd_rn(__fmul_rn(fx,fx), __fmul_rn(fy,fy)), __fmul_rn(fz,fz)));
        float dn = fmaxf(nr, 1e-8f);
        tvx[i] = __fdiv_rn(fx, dn);
        tvy[i] = __fdiv_rn(fy, dn);
        tvz[i] = __fdiv_rn(fz, dn);
    }
    __syncthreads();
    int sg = blockIdx.x * 256 + t;   // 0..4095
    float vx = vp[(size_t)sg*3 + 0];
    float vy = vp[(size_t)sg*3 + 1];
    float vz = vp[(size_t)sg*3 + 2];

    float nr = __fsqrt_rn(__fadd_rn(__fadd_rn(__fmul_rn(vx,vx), __fmul_rn(vy,vy)), __fmul_rn(vz,vz)));
    float dn = fmaxf(nr, 1e-8f);
    float ux = __fdiv_rn(vx, dn), uy = __fdiv_rn(vy, dn), uz = __fdiv_rn(vz, dn);
    float best = -INFINITY; int bidx = 0;
    for (int v = 0; v < NV; ++v) {
        float c = __fadd_rn(__fadd_rn(__fmul_rn(ux, tvx[v]), __fmul_rn(uy, tvy[v])), __fmul_rn(uz, tvz[v]));
        if (c > best) { best = c; bidx = v; }
    }
    o7[sg] = (float)bidx;

    // vp_rot: towards = -vp
    float axx = -vx, axy = -vy, axz = -vz;
    float ayx = vy, ayy = -vx, ayz = 0.f;          // ay = [-ax.y, ax.x, 0]
    float s2 = __fadd_rn(__fadd_rn(__fmul_rn(ayx,ayx), __fmul_rn(ayy,ayy)), 0.f);
    if (s2 == 0.f) { ayx = 0.f; ayy = 1.f; ayz = 0.f; }
    float an = __fsqrt_rn(__fadd_rn(__fadd_rn(__fmul_rn(axx,axx), __fmul_rn(axy,axy)), __fmul_rn(axz,axz)));
    float nx0 = __fdiv_rn(axx, an), nx1 = __fdiv_rn(axy, an), nx2 = __fdiv_rn(axz, an);
    float bn2 = __fsqrt_rn(__fadd_rn(__fadd_rn(__fmul_rn(ayx,ayx), __fmul_rn(ayy,ayy)), __fmul_rn(ayz,ayz)));
    float ny0 = __fdiv_rn(ayx, bn2), ny1 = __fdiv_rn(ayy, bn2), ny2 = __fdiv_rn(ayz, bn2);
    float nz0 = __fsub_rn(__fmul_rn(nx1, ny2), __fmul_rn(nx2, ny1));
    float nz1 = __fsub_rn(__fmul_rn(nx2, ny0), __fmul_rn(nx0, ny2));
    float nz2 = __fsub_rn(__fmul_rn(nx0, ny1), __fmul_rn(nx1, ny0));
    size_t o = (size_t)sg * 9;   // rows = (nx_i, ny_i, nz_i)
    o8[o+0] = nx0; o8[o+1] = ny0; o8[o+2] = nz0;
    o8[o+3] = nx1; o8[o+4] = ny1; o8[o+5] = nz1;
    o8[o+6] = nx2; o8[o+7] = ny2; o8[o+8] = nz2;
}

// ---------------------------------------------------------------------------
extern "C" void kernel_launch(void* const* d_in, const int* in_sizes, int n_in,
                              void* d_out, int out_size, void* d_ws, size_t ws_size,
                              hipStream_t stream) {
    const float* xyz   = (const float*)d_in[0];
    const float* feats = (const float*)d_in[1];
    const float* gh_w1 = (const float*)d_in[2];
    const float* gh_b1 = (const float*)d_in[3];
    const float* gh_g  = (const float*)d_in[4];
    const float* gh_be = (const float*)d_in[5];
    const float* gh_m  = (const float*)d_in[6];
    const float* gh_v  = (const float*)d_in[7];
    const float* gh_w2 = (const float*)d_in[8];
    const float* gh_b2 = (const float*)d_in[9];
    const float* c1_w  = (const float*)d_in[10];
    const float* c1_b  = (const float*)d_in[11];
    const float* bn_g  = (const float*)d_in[12];
    const float* bn_b  = (const float*)d_in[13];
    const float* bn_m  = (const float*)d_in[14];
    const float* bn_v  = (const float*)d_in[15];
    const float* c2_w  = (const float*)d_in[16];
    const float* c2_b  = (const float*)d_in[17];

    float* out = (float*)d_out;
    float* o0 = out + O0;
    float* o1 = out + O1;
    float* o2 = out + O2;
    float* o3 = out + O3;
    float* o4 = out + O4;
    float* o5 = out + O5;
    float* o6 = out + O6;
    float* o7 = out + O7;
    float* o8 = out + O8;

    char* ws = (char*)d_ws;
    size_t off = 0;
    auto take = [&](size_t bytes) -> char* {
        char* p = ws + off;
        off = (off + bytes + 255) & ~(size_t)255;
        return p;
    };
    unsigned char* maskp = (unsigned char*)take((size_t)BB*NN);
    int*   cntp  = (int*)take((size_t)BB*4);
    int*   corig = (int*)take((size_t)BB*NN*4);
    float* cx    = (float*)take((size_t)BB*NN*4);
    float* cy    = (float*)take((size_t)BB*NN*4);
    float* cz    = (float*)take((size_t)BB*NN*4);
    int*   indsp = (int*)take((size_t)BB*SS*4);
    int*   donep = (int*)take(64);

    // 1) fused conv+bn+relu+conv over all N points
    gemm_fused<<<dim3((NN + TN - 1)/TN, BB), 256, 0, stream>>>(
        feats, NN, NN, gh_w1, gh_b1, gh_g, gh_be, gh_m, gh_v, gh_w2, gh_b2,
        0, o0, o1, maskp, nullptr);

    // 2) compact masked-in candidates (order-preserving)
    compact_kernel<<<dim3(BB), 256, 0, stream>>>(maskp, xyz, cntp, corig, cx, cy, cz);

    // 3) sequential FPS over candidates (+ clock-warm blocks)
    hipMemsetAsync(donep, 0, 4, stream);
    fps_kernel<<<dim3(256), FPS_T, 0, stream>>>(cntp, corig, cx, cy, cz, o3, indsp, donep);

    // 4) gathers
    gather_kernel<<<dim3((BB*CC*SS)/256), 256, 0, stream>>>(xyz, feats, o1, indsp, o2, o4, o5);

    // 5) second fused conv stack -> vp_xyz
    gemm_fused<<<dim3(SS/TN, BB), 256, 0, stream>>>(
        o4, SS, SS, c1_w, c1_b, bn_g, bn_b, bn_m, bn_v, c2_w, c2_b,
        1, nullptr, nullptr, nullptr, o6);

    // 6) view argmax + rotation matrices
    view_rot_kernel<<<dim3((BB*SS)/256), 256, 0, stream>>>(o6, o7, o8);
}

// Round 4
// 1223.570 us; speedup vs baseline: 2.6068x; 1.3643x over previous
//
#include <hip/hip_runtime.h>
#include <hip/hip_bf16.h>
#include <math.h>

static constexpr int BB = 4;
static constexpr int NN = 20000;
static constexpr int CC = 256;
static constexpr int SS = 1024;   // NUM_SAMPLE
static constexpr int NV = 300;    // NUM_VIEW

// output offsets (floats) in d_out, concatenated in reference return order
static constexpr size_t O0 = 0;                     // objectness (B,2,N)
static constexpr size_t O1 = O0 + (size_t)BB*2*NN;  // graspness (B,N)
static constexpr size_t O2 = O1 + (size_t)BB*NN;    // graspable_xyz (B,S,3)
static constexpr size_t O3 = O2 + (size_t)BB*SS*3;  // graspable_inds (B,S) as float
static constexpr size_t O4 = O3 + (size_t)BB*SS;    // graspable_features (B,C,S)
static constexpr size_t O5 = O4 + (size_t)BB*CC*SS; // fp2_graspness (B,S)
static constexpr size_t O6 = O5 + (size_t)BB*SS;    // vp_xyz (B,S,3)
static constexpr size_t O7 = O6 + (size_t)BB*SS*3;  // top_view_inds (B,S) as float
static constexpr size_t O8 = O7 + (size_t)BB*SS;    // vp_rot (B,S,3,3)

// ---------------------------------------------------------------------------
// Fused GEMM: out3ch = W2(3x256) @ relu(bn(W1(256x256) @ X + b1)) + b2
// mode 0: write objectness/graspness/mask   mode 1: write vp_xyz (B,S,3)
// ---------------------------------------------------------------------------
static constexpr int TN = 64;     // columns per block
static constexpr int KC = 32;     // k-chunk
static constexpr int SW_LD = 260; // padded LDS row for sW[k][m]
static constexpr int PS_LD = 68;  // padded LDS row for psum

__global__ __launch_bounds__(256, 2) void gemm_fused(
    const float* __restrict__ X, int ncols, int cstride,
    const float* __restrict__ W1, const float* __restrict__ B1v,
    const float* __restrict__ Gv, const float* __restrict__ BEv,
    const float* __restrict__ Mv, const float* __restrict__ Vv,
    const float* __restrict__ W2, const float* __restrict__ B2v,
    int mode, float* __restrict__ o0, float* __restrict__ o1,
    unsigned char* __restrict__ maskp, float* __restrict__ vp)
{
    __shared__ alignas(16) char smem_raw[KC*SW_LD*4 + KC*TN*4]; // 41472 B (phase2 aliases)
    float* sW   = (float*)smem_raw;                       // [KC][SW_LD]
    float* sF   = (float*)(smem_raw + KC*SW_LD*4);        // [KC][TN]
    float* psum = (float*)smem_raw;                       // [3][32][PS_LD] = 26112 B
    float* gout = (float*)(smem_raw + 3*32*PS_LD*4);      // [3][64]

    const int t  = threadIdx.x;
    const int b  = blockIdx.y;
    const int n0 = blockIdx.x * TN;
    const int tm = t & 31;   // 32 groups along M (8 rows each)
    const int tn = t >> 5;   // 8 groups along N (8 cols each)

    const float* Xb = X + (size_t)b * CC * cstride;

    float acc[8][8];
#pragma unroll
    for (int i = 0; i < 8; ++i)
#pragma unroll
        for (int j = 0; j < 8; ++j) acc[i][j] = 0.f;

    for (int k0 = 0; k0 < CC; k0 += KC) {
        // stage W1 tile (256 x KC), transposed into sW[k][m]
#pragma unroll
        for (int r = 0; r < (CC*KC)/256; ++r) {
            int idx = r*256 + t;
            int m  = idx >> 5;
            int kk = idx & 31;
            sW[kk*SW_LD + m] = W1[m*CC + k0 + kk];
        }
        // stage X tile (KC x 64)
#pragma unroll
        for (int r = 0; r < (KC*TN)/256; ++r) {
            int idx = r*256 + t;
            int kk = idx >> 6;
            int j  = idx & 63;
            int col = n0 + j;
            float v = 0.f;
            if (col < ncols) v = Xb[(size_t)(k0+kk)*cstride + col];
            sF[kk*TN + j] = v;
        }
        __syncthreads();
#pragma unroll 8
        for (int kk = 0; kk < KC; ++kk) {
            const float4 a0 = *(const float4*)(sW + kk*SW_LD + tm*8);
            const float4 a1 = *(const float4*)(sW + kk*SW_LD + tm*8 + 4);
            const float4 f0 = *(const float4*)(sF + kk*TN + tn*8);
            const float4 f1 = *(const float4*)(sF + kk*TN + tn*8 + 4);
            float av[8] = {a0.x,a0.y,a0.z,a0.w,a1.x,a1.y,a1.z,a1.w};
            float bv[8] = {f0.x,f0.y,f0.z,f0.w,f1.x,f1.y,f1.z,f1.w};
#pragma unroll
            for (int i = 0; i < 8; ++i)
#pragma unroll
                for (int j = 0; j < 8; ++j)
                    acc[i][j] = fmaf(av[i], bv[j], acc[i][j]);
        }
        __syncthreads();
    }

    // epilogue: bias + bn + relu in registers, partial W2 contraction
    float part[3][8];
#pragma unroll
    for (int r = 0; r < 3; ++r)
#pragma unroll
        for (int j = 0; j < 8; ++j) part[r][j] = 0.f;

#pragma unroll
    for (int i = 0; i < 8; ++i) {
        int m = tm*8 + i;
        float scale = __fdiv_rn(Gv[m], __fsqrt_rn(__fadd_rn(Vv[m], 1e-5f)));
        float shift = __fsub_rn(BEv[m], __fmul_rn(Mv[m], scale));
        float w0 = W2[m], w1 = W2[CC + m], w2 = W2[2*CC + m];
        float b1m = B1v[m];
#pragma unroll
        for (int j = 0; j < 8; ++j) {
            float x = __fadd_rn(acc[i][j], b1m);
            float y = __fadd_rn(__fmul_rn(x, scale), shift);
            float h = y > 0.f ? y : 0.f;
            part[0][j] = fmaf(w0, h, part[0][j]);
            part[1][j] = fmaf(w1, h, part[1][j]);
            part[2][j] = fmaf(w2, h, part[2][j]);
        }
    }
#pragma unroll
    for (int r = 0; r < 3; ++r) {
        float4 p0 = {part[r][0], part[r][1], part[r][2], part[r][3]};
        float4 p1 = {part[r][4], part[r][5], part[r][6], part[r][7]};
        *(float4*)(psum + (r*32 + tm)*PS_LD + tn*8)     = p0;
        *(float4*)(psum + (r*32 + tm)*PS_LD + tn*8 + 4) = p1;
    }
    __syncthreads();
    if (t < 192) {
        int r = t >> 6, col = t & 63;
        float s = 0.f;
#pragma unroll
        for (int w = 0; w < 32; ++w) s = __fadd_rn(s, psum[(r*32 + w)*PS_LD + col]);
        float tot = __fadd_rn(s, B2v[r]);
        if (mode == 0) {
            gout[r*64 + col] = tot;
        } else {
            vp[((size_t)b*SS + n0 + col)*3 + r] = tot;
        }
    }
    if (mode == 0) {
        __syncthreads();
        if (t < 64) {
            int n = n0 + t;
            if (n < ncols) {
                float v0 = gout[t], v1 = gout[64 + t], v2 = gout[128 + t];
                o0[(size_t)b*2*ncols + n]         = v0;
                o0[(size_t)b*2*ncols + ncols + n] = v1;
                o1[(size_t)b*ncols + n]           = v2;
                maskp[(size_t)b*ncols + n] = (v2 > 0.1f && v1 > v0) ? 1 : 0;
            }
        }
    }
}

// ---------------------------------------------------------------------------
// Order-preserving stream compaction of masked-in candidates
// ---------------------------------------------------------------------------
__global__ __launch_bounds__(256) void compact_kernel(
    const unsigned char* __restrict__ maskp, const float* __restrict__ xyz,
    int* __restrict__ cntp, int* __restrict__ corig,
    float* __restrict__ cx, float* __restrict__ cy, float* __restrict__ cz)
{
    const int b = blockIdx.x;
    const int t = threadIdx.x;
    __shared__ int wsum[4];
    __shared__ int running;
    if (t == 0) running = 0;
    __syncthreads();
    const unsigned char* mb = maskp + (size_t)b*NN;
    const size_t bofs = (size_t)b*NN;
    for (int base = 0; base < NN; base += 256) {
        int i = base + t;
        int m = (i < NN) ? (int)mb[i] : 0;
        unsigned long long bal = __ballot(m != 0);
        int lane = t & 63, w = t >> 6;
        int pre = __popcll(bal & ((1ull << lane) - 1ull));
        if (lane == 0) wsum[w] = __popcll(bal);
        __syncthreads();
        int offs = running;
        for (int ww = 0; ww < w; ++ww) offs += wsum[ww];
        if (m) {
            int pos = offs + pre;
            corig[bofs + pos] = i;
            cx[bofs + pos] = xyz[(bofs + i)*3 + 0];
            cy[bofs + pos] = xyz[(bofs + i)*3 + 1];
            cz[bofs + pos] = xyz[(bofs + i)*3 + 2];
        }
        __syncthreads();
        if (t == 0) running += wsum[0] + wsum[1] + wsum[2] + wsum[3];
    }
    __syncthreads();
    if (t == 0) cntp[b] = running;
}

// ---------------------------------------------------------------------------
// Masked FPS. Grid = 256 blocks x 256 threads: blocks [0,BB) run the serial
// FPS (4 waves = 1 wave/SIMD: minimal barrier skew, minimal redundant-reduce
// issue). Blocks [BB,256) keep the GPU "busy" at ~11% VALU duty
// (16 FMA + s_sleep(8)) so DPM holds SCLK without power-capping the chip.
//
// Wave argmax: pack u64 key = (bits(d)<<32)|(~idx)  (monotone in d, tie ->
// lowest idx, keys unique), then 6 DPP steps of {2x dpp-mov, v_cmp_lt_u64,
// 2x cndmask} -> lane 63 holds wave best. Cross-wave: 4 keys in LDS,
// depth-2 u64 max tree. Scan loop is templated on ceil(cnt/256) so only
// existing slots burn instructions (no data-dependent break -> stays in VGPRs).
// ---------------------------------------------------------------------------
static constexpr int FPS_T = 256;
static constexpr int KAMAX = 20;            // max slots/thread (path A)
static constexpr int CAPA  = FPS_T * KAMAX; // 5120

template<int CTRL>
__device__ __forceinline__ unsigned long long dpp_umax(unsigned long long k) {
    int lo = __builtin_amdgcn_update_dpp(0, (int)(unsigned)k,         CTRL, 0xf, 0xf, false);
    int hi = __builtin_amdgcn_update_dpp(0, (int)(unsigned)(k >> 32), CTRL, 0xf, 0xf, false);
    unsigned long long ok = ((unsigned long long)(unsigned)hi << 32) | (unsigned)lo;
    return ok > k ? ok : k;
}

__device__ __forceinline__ unsigned long long wave_umax_dpp(unsigned long long k) {
    k = dpp_umax<0x111>(k);  // row_shr:1
    k = dpp_umax<0x112>(k);  // row_shr:2
    k = dpp_umax<0x114>(k);  // row_shr:4
    k = dpp_umax<0x118>(k);  // row_shr:8
    k = dpp_umax<0x142>(k);  // row_bcast:15
    k = dpp_umax<0x143>(k);  // row_bcast:31  -> lane 63 has wave max
    return k;
}

__device__ __forceinline__ unsigned long long pack_key(float v, int i) {
    unsigned long long k = (((unsigned long long)__float_as_uint(v)) << 32)
                         | (unsigned long long)(0xFFFFFFFFu - (unsigned)i);
    return (v == -INFINITY) ? 0ull : k;
}

template<int KAT>
__device__ __forceinline__ void fps_scan_loop(
    int cnt, const float* __restrict__ cxb, const float* __restrict__ cyb,
    const float* __restrict__ czb, const float* __restrict__ sxyz,
    unsigned long long (*swk)[4], int* __restrict__ whist)
{
    const int t = threadIdx.x;
    const int wave = t >> 6, lane = t & 63;

    float X[KAT], Y[KAT], Z[KAT], D[KAT];
#pragma unroll
    for (int j = 0; j < KAT; ++j) {
        int g = t + (j << 8);
        bool v = g < cnt;
        X[j] = v ? cxb[g] : 0.f;
        Y[j] = v ? cyb[g] : 0.f;
        Z[j] = v ? czb[g] : 0.f;
        D[j] = v ? 1e10f : -INFINITY;
    }

    float px = cxb[0], py = cyb[0], pz = czb[0];

    for (int it = 1; it < SS; ++it) {
        float bv = -INFINITY; int bi = 0x7fffffff;
#pragma unroll
        for (int j = 0; j < KAT; ++j) {
            float dx = __fsub_rn(X[j], px);
            float dy = __fsub_rn(Y[j], py);
            float dz = __fsub_rn(Z[j], pz);
            float d  = __fadd_rn(__fadd_rn(__fmul_rn(dx,dx), __fmul_rn(dy,dy)), __fmul_rn(dz,dz));
            float dn = fminf(D[j], d);
            D[j] = dn;
            if (dn > bv) { bv = dn; bi = t + (j << 8); }
        }
        unsigned long long key = wave_umax_dpp(pack_key(bv, bi));
        int par = it & 1;
        if (lane == 63) swk[par][wave] = key;
        __syncthreads();
        const ulonglong2* kp = (const ulonglong2*)&swk[par][0];
        ulonglong2 kA = kp[0], kB = kp[1];
        unsigned long long m0 = kA.x > kA.y ? kA.x : kA.y;
        unsigned long long m1 = kB.x > kB.y ? kB.x : kB.y;
        unsigned long long best = m0 > m1 ? m0 : m1;
        int wi = (int)(0xFFFFFFFFu - (unsigned)(best & 0xFFFFFFFFull));
        float4 w4 = *(const float4*)&sxyz[wi*4];
        px = w4.x; py = w4.y; pz = w4.z;
        if (t == 0) whist[it] = wi;
    }
}

__global__ __launch_bounds__(FPS_T, 1) void fps_kernel(
    const int* __restrict__ cntp, const int* __restrict__ corig,
    const float* __restrict__ cx, const float* __restrict__ cy, const float* __restrict__ cz,
    float* __restrict__ o3, int* __restrict__ oi, int* __restrict__ donep)
{
    const int t = threadIdx.x;

    __shared__ alignas(16) float sxyz[CAPA*4];                // 80 KiB (path B aliases D[] here)
    __shared__ alignas(16) unsigned long long swk[2][4];
    __shared__ int whist[SS];
    __shared__ int sdone;

    if (blockIdx.x >= BB) {
        // ------ clock-warm block: resident but low power (~11% duty) ------
        if (t == 0) sdone = 0;
        __syncthreads();
        float a = 1.0f + (float)t * 1e-6f, bm = 1.0000001f, c = 0.f;
        for (int iter = 0; iter < 20000; ++iter) {
#pragma unroll
            for (int u = 0; u < 16; ++u) c = fmaf(a, bm, c);
            __builtin_amdgcn_s_sleep(8);
            if (t == 0 && (iter & 7) == 0) {
                if (__hip_atomic_load(donep, __ATOMIC_RELAXED, __HIP_MEMORY_SCOPE_AGENT) >= BB)
                    *(volatile int*)&sdone = 1;
            }
            if (*(volatile int*)&sdone) break;
        }
        if (t == 0) donep[4 + (blockIdx.x & 3)] = __float_as_int(c);  // keep c live (scratch)
        return;
    }

    const int b = blockIdx.x;
    const int cnt = cntp[b];
    const size_t bofs = (size_t)b*NN;
    float* o3b = o3 + (size_t)b*SS;
    int*   oib = oi + (size_t)b*SS;
    const int wave = t >> 6, lane = t & 63;

    if (cnt <= 0) {
        for (int s = t; s < SS; s += FPS_T) { o3b[s] = 0.f; oib[s] = 0; }
        if (t == 0) __hip_atomic_fetch_add(donep, 1, __ATOMIC_RELEASE, __HIP_MEMORY_SCOPE_AGENT);
        return;
    }

    if (t == 0) whist[0] = 0;          // first selected = compacted index 0

    if (cnt <= CAPA) {
        // ---------------- Path A: registers + packed LDS xyz mirror ----------------
        for (int g = t; g < cnt; g += FPS_T) {
            float4 w4 = { cx[bofs + g], cy[bofs + g], cz[bofs + g], 0.f };
            *(float4*)&sxyz[g*4] = w4;
        }
        // (first in-loop __syncthreads covers staging visibility before sxyz reads)
        int kat2 = ((cnt + 255) >> 8);
        kat2 = (kat2 + 1) & ~1;        // round up to even: 2..20
        const float* cxb = cx + bofs;
        const float* cyb = cy + bofs;
        const float* czb = cz + bofs;
        switch (kat2) {
            case 2:  fps_scan_loop<2 >(cnt, cxb, cyb, czb, sxyz, swk, whist); break;
            case 4:  fps_scan_loop<4 >(cnt, cxb, cyb, czb, sxyz, swk, whist); break;
            case 6:  fps_scan_loop<6 >(cnt, cxb, cyb, czb, sxyz, swk, whist); break;
            case 8:  fps_scan_loop<8 >(cnt, cxb, cyb, czb, sxyz, swk, whist); break;
            case 10: fps_scan_loop<10>(cnt, cxb, cyb, czb, sxyz, swk, whist); break;
            case 12: fps_scan_loop<12>(cnt, cxb, cyb, czb, sxyz, swk, whist); break;
            case 14: fps_scan_loop<14>(cnt, cxb, cyb, czb, sxyz, swk, whist); break;
            case 16: fps_scan_loop<16>(cnt, cxb, cyb, czb, sxyz, swk, whist); break;
            case 18: fps_scan_loop<18>(cnt, cxb, cyb, czb, sxyz, swk, whist); break;
            default: fps_scan_loop<20>(cnt, cxb, cyb, czb, sxyz, swk, whist); break;
        }
    } else {
        // ---------------- Path B: LDS distances, streamed xyz (fallback) ---------------
        float* Dl = sxyz;
        for (int g = t; g < cnt; g += FPS_T) Dl[g] = 1e10f;
        __syncthreads();

        float px = cx[bofs], py = cy[bofs], pz = cz[bofs];

        for (int it = 1; it < SS; ++it) {
            float bv = -INFINITY; int bi = 0x7fffffff;
            for (int g = t; g < cnt; g += FPS_T) {
                float dx = __fsub_rn(cx[bofs + g], px);
                float dy = __fsub_rn(cy[bofs + g], py);
                float dz = __fsub_rn(cz[bofs + g], pz);
                float d  = __fadd_rn(__fadd_rn(__fmul_rn(dx,dx), __fmul_rn(dy,dy)), __fmul_rn(dz,dz));
                float dn = fminf(Dl[g], d);
                Dl[g] = dn;
                if (dn > bv) { bv = dn; bi = g; }
            }
            unsigned long long key = wave_umax_dpp(pack_key(bv, bi));
            int par = it & 1;
            if (lane == 63) swk[par][wave] = key;
            __syncthreads();
            const ulonglong2* kp = (const ulonglong2*)&swk[par][0];
            ulonglong2 kA = kp[0], kB = kp[1];
            unsigned long long m0 = kA.x > kA.y ? kA.x : kA.y;
            unsigned long long m1 = kB.x > kB.y ? kB.x : kB.y;
            unsigned long long best = m0 > m1 ? m0 : m1;
            int wi = (int)(0xFFFFFFFFu - (unsigned)(best & 0xFFFFFFFFull));
            px = cx[bofs + wi]; py = cy[bofs + wi]; pz = cz[bofs + wi];
            if (t == 0) whist[it] = wi;
        }
    }

    __syncthreads();   // make whist[] fully visible
    for (int s = t; s < SS; s += FPS_T) {
        int wi  = whist[s];
        int org = corig[bofs + wi];
        oib[s] = org;
        o3b[s] = (float)org;
    }
    if (t == 0) __hip_atomic_fetch_add(donep, 1, __ATOMIC_RELEASE, __HIP_MEMORY_SCOPE_AGENT);
}

// ---------------------------------------------------------------------------
// Gathers: graspable_xyz, graspable_features, fp2_graspness
// ---------------------------------------------------------------------------
__global__ __launch_bounds__(256) void gather_kernel(
    const float* __restrict__ xyz, const float* __restrict__ feats,
    const float* __restrict__ grasp, const int* __restrict__ inds,
    float* __restrict__ o2, float* __restrict__ o4, float* __restrict__ o5)
{
    int e = blockIdx.x * 256 + threadIdx.x;   // B*C*S = 1,048,576 exactly
    int b = e >> 18;
    int r = e & ((1 << 18) - 1);
    int c = r >> 10;
    int s = r & 1023;
    int idx = inds[(b << 10) + s];
    o4[e] = feats[((size_t)b*CC + c)*NN + idx];
    if (c == 0) {
        o5[(b << 10) + s] = grasp[(size_t)b*NN + idx];
        size_t src = ((size_t)b*NN + idx)*3;
        size_t dst = ((size_t)(b << 10) + s)*3;
        o2[dst + 0] = xyz[src + 0];
        o2[dst + 1] = xyz[src + 1];
        o2[dst + 2] = xyz[src + 2];
    }
}

// ---------------------------------------------------------------------------
// top_view argmax + vp_rot
// ---------------------------------------------------------------------------
__global__ __launch_bounds__(256) void view_rot_kernel(
    const float* __restrict__ vp, float* __restrict__ o7, float* __restrict__ o8)
{
    __shared__ float tvx[NV], tvy[NV], tvz[NV];
    int t = threadIdx.x;
    for (int i = t; i < NV; i += 256) {
        double phi = (sqrt(5.0) - 1.0) * 0.5;
        double zd  = (2.0*(double)i + 1.0)/300.0 - 1.0;
        double rr  = sqrt(fmax(1.0 - zd*zd, 0.0));
        double ang = 2.0 * 3.14159265358979323846 * (double)i * phi;
        float fx = (float)(rr * cos(ang));
        float fy = (float)(rr * sin(ang));
        float fz = (float)zd;
        float nr = __fsqrt_rn(__fadd_rn(__fadd_rn(__fmul_rn(fx,fx), __fmul_rn(fy,fy)), __fmul_rn(fz,fz)));
        float dn = fmaxf(nr, 1e-8f);
        tvx[i] = __fdiv_rn(fx, dn);
        tvy[i] = __fdiv_rn(fy, dn);
        tvz[i] = __fdiv_rn(fz, dn);
    }
    __syncthreads();
    int sg = blockIdx.x * 256 + t;   // 0..4095
    float vx = vp[(size_t)sg*3 + 0];
    float vy = vp[(size_t)sg*3 + 1];
    float vz = vp[(size_t)sg*3 + 2];

    float nr = __fsqrt_rn(__fadd_rn(__fadd_rn(__fmul_rn(vx,vx), __fmul_rn(vy,vy)), __fmul_rn(vz,vz)));
    float dn = fmaxf(nr, 1e-8f);
    float ux = __fdiv_rn(vx, dn), uy = __fdiv_rn(vy, dn), uz = __fdiv_rn(vz, dn);
    float best = -INFINITY; int bidx = 0;
    for (int v = 0; v < NV; ++v) {
        float c = __fadd_rn(__fadd_rn(__fmul_rn(ux, tvx[v]), __fmul_rn(uy, tvy[v])), __fmul_rn(uz, tvz[v]));
        if (c > best) { best = c; bidx = v; }
    }
    o7[sg] = (float)bidx;

    // vp_rot: towards = -vp
    float axx = -vx, axy = -vy, axz = -vz;
    float ayx = vy, ayy = -vx, ayz = 0.f;          // ay = [-ax.y, ax.x, 0]
    float s2 = __fadd_rn(__fadd_rn(__fmul_rn(ayx,ayx), __fmul_rn(ayy,ayy)), 0.f);
    if (s2 == 0.f) { ayx = 0.f; ayy = 1.f; ayz = 0.f; }
    float an = __fsqrt_rn(__fadd_rn(__fadd_rn(__fmul_rn(axx,axx), __fmul_rn(axy,axy)), __fmul_rn(axz,axz)));
    float nx0 = __fdiv_rn(axx, an), nx1 = __fdiv_rn(axy, an), nx2 = __fdiv_rn(axz, an);
    float bn2 = __fsqrt_rn(__fadd_rn(__fadd_rn(__fmul_rn(ayx,ayx), __fmul_rn(ayy,ayy)), __fmul_rn(ayz,ayz)));
    float ny0 = __fdiv_rn(ayx, bn2), ny1 = __fdiv_rn(ayy, bn2), ny2 = __fdiv_rn(ayz, bn2);
    float nz0 = __fsub_rn(__fmul_rn(nx1, ny2), __fmul_rn(nx2, ny1));
    float nz1 = __fsub_rn(__fmul_rn(nx2, ny0), __fmul_rn(nx0, ny2));
    float nz2 = __fsub_rn(__fmul_rn(nx0, ny1), __fmul_rn(nx1, ny0));
    size_t o = (size_t)sg * 9;   // rows = (nx_i, ny_i, nz_i)
    o8[o+0] = nx0; o8[o+1] = ny0; o8[o+2] = nz0;
    o8[o+3] = nx1; o8[o+4] = ny1; o8[o+5] = nz1;
    o8[o+6] = nx2; o8[o+7] = ny2; o8[o+8] = nz2;
}

// ---------------------------------------------------------------------------
extern "C" void kernel_launch(void* const* d_in, const int* in_sizes, int n_in,
                              void* d_out, int out_size, void* d_ws, size_t ws_size,
                              hipStream_t stream) {
    const float* xyz   = (const float*)d_in[0];
    const float* feats = (const float*)d_in[1];
    const float* gh_w1 = (const float*)d_in[2];
    const float* gh_b1 = (const float*)d_in[3];
    const float* gh_g  = (const float*)d_in[4];
    const float* gh_be = (const float*)d_in[5];
    const float* gh_m  = (const float*)d_in[6];
    const float* gh_v  = (const float*)d_in[7];
    const float* gh_w2 = (const float*)d_in[8];
    const float* gh_b2 = (const float*)d_in[9];
    const float* c1_w  = (const float*)d_in[10];
    const float* c1_b  = (const float*)d_in[11];
    const float* bn_g  = (const float*)d_in[12];
    const float* bn_b  = (const float*)d_in[13];
    const float* bn_m  = (const float*)d_in[14];
    const float* bn_v  = (const float*)d_in[15];
    const float* c2_w  = (const float*)d_in[16];
    const float* c2_b  = (const float*)d_in[17];

    float* out = (float*)d_out;
    float* o0 = out + O0;
    float* o1 = out + O1;
    float* o2 = out + O2;
    float* o3 = out + O3;
    float* o4 = out + O4;
    float* o5 = out + O5;
    float* o6 = out + O6;
    float* o7 = out + O7;
    float* o8 = out + O8;

    char* ws = (char*)d_ws;
    size_t off = 0;
    auto take = [&](size_t bytes) -> char* {
        char* p = ws + off;
        off = (off + bytes + 255) & ~(size_t)255;
        return p;
    };
    unsigned char* maskp = (unsigned char*)take((size_t)BB*NN);
    int*   cntp  = (int*)take((size_t)BB*4);
    int*   corig = (int*)take((size_t)BB*NN*4);
    float* cx    = (float*)take((size_t)BB*NN*4);
    float* cy    = (float*)take((size_t)BB*NN*4);
    float* cz    = (float*)take((size_t)BB*NN*4);
    int*   indsp = (int*)take((size_t)BB*SS*4);
    int*   donep = (int*)take(64);

    // 1) fused conv+bn+relu+conv over all N points
    gemm_fused<<<dim3((NN + TN - 1)/TN, BB), 256, 0, stream>>>(
        feats, NN, NN, gh_w1, gh_b1, gh_g, gh_be, gh_m, gh_v, gh_w2, gh_b2,
        0, o0, o1, maskp, nullptr);

    // 2) compact masked-in candidates (order-preserving)
    compact_kernel<<<dim3(BB), 256, 0, stream>>>(maskp, xyz, cntp, corig, cx, cy, cz);

    // 3) sequential FPS over candidates (+ low-duty clock-warm blocks)
    hipMemsetAsync(donep, 0, 4, stream);
    fps_kernel<<<dim3(256), FPS_T, 0, stream>>>(cntp, corig, cx, cy, cz, o3, indsp, donep);

    // 4) gathers
    gather_kernel<<<dim3((BB*CC*SS)/256), 256, 0, stream>>>(xyz, feats, o1, indsp, o2, o4, o5);

    // 5) second fused conv stack -> vp_xyz
    gemm_fused<<<dim3(SS/TN, BB), 256, 0, stream>>>(
        o4, SS, SS, c1_w, c1_b, bn_g, bn_b, bn_m, bn_v, c2_w, c2_b,
        1, nullptr, nullptr, nullptr, o6);

    // 6) view argmax + rotation matrices
    view_rot_kernel<<<dim3((BB*SS)/256), 256, 0, stream>>>(o6, o7, o8);
}

// Round 5
// 1205.719 us; speedup vs baseline: 2.6454x; 1.0148x over previous
//
#include <hip/hip_runtime.h>
#include <hip/hip_bf16.h>
#include <math.h>

static constexpr int BB = 4;
static constexpr int NN = 20000;
static constexpr int CC = 256;
static constexpr int SS = 1024;   // NUM_SAMPLE
static constexpr int NV = 300;    // NUM_VIEW

// output offsets (floats) in d_out, concatenated in reference return order
static constexpr size_t O0 = 0;                     // objectness (B,2,N)
static constexpr size_t O1 = O0 + (size_t)BB*2*NN;  // graspness (B,N)
static constexpr size_t O2 = O1 + (size_t)BB*NN;    // graspable_xyz (B,S,3)
static constexpr size_t O3 = O2 + (size_t)BB*SS*3;  // graspable_inds (B,S) as float
static constexpr size_t O4 = O3 + (size_t)BB*SS;    // graspable_features (B,C,S)
static constexpr size_t O5 = O4 + (size_t)BB*CC*SS; // fp2_graspness (B,S)
static constexpr size_t O6 = O5 + (size_t)BB*SS;    // vp_xyz (B,S,3)
static constexpr size_t O7 = O6 + (size_t)BB*SS*3;  // top_view_inds (B,S) as float
static constexpr size_t O8 = O7 + (size_t)BB*SS;    // vp_rot (B,S,3,3)

// ---------------------------------------------------------------------------
// Fused GEMM: out3ch = W2(3x256) @ relu(bn(W1(256x256) @ X + b1)) + b2
// mode 0: write objectness/graspness/mask   mode 1: write vp_xyz (B,S,3)
// ---------------------------------------------------------------------------
static constexpr int TN = 64;     // columns per block
static constexpr int KC = 32;     // k-chunk
static constexpr int SW_LD = 260; // padded LDS row for sW[k][m]
static constexpr int PS_LD = 68;  // padded LDS row for psum

__global__ __launch_bounds__(256, 2) void gemm_fused(
    const float* __restrict__ X, int ncols, int cstride,
    const float* __restrict__ W1, const float* __restrict__ B1v,
    const float* __restrict__ Gv, const float* __restrict__ BEv,
    const float* __restrict__ Mv, const float* __restrict__ Vv,
    const float* __restrict__ W2, const float* __restrict__ B2v,
    int mode, float* __restrict__ o0, float* __restrict__ o1,
    unsigned char* __restrict__ maskp, float* __restrict__ vp)
{
    __shared__ alignas(16) char smem_raw[KC*SW_LD*4 + KC*TN*4]; // 41472 B (phase2 aliases)
    float* sW   = (float*)smem_raw;                       // [KC][SW_LD]
    float* sF   = (float*)(smem_raw + KC*SW_LD*4);        // [KC][TN]
    float* psum = (float*)smem_raw;                       // [3][32][PS_LD] = 26112 B
    float* gout = (float*)(smem_raw + 3*32*PS_LD*4);      // [3][64]

    const int t  = threadIdx.x;
    const int b  = blockIdx.y;
    const int n0 = blockIdx.x * TN;
    const int tm = t & 31;   // 32 groups along M (8 rows each)
    const int tn = t >> 5;   // 8 groups along N (8 cols each)

    const float* Xb = X + (size_t)b * CC * cstride;

    float acc[8][8];
#pragma unroll
    for (int i = 0; i < 8; ++i)
#pragma unroll
        for (int j = 0; j < 8; ++j) acc[i][j] = 0.f;

    for (int k0 = 0; k0 < CC; k0 += KC) {
        // stage W1 tile (256 x KC), transposed into sW[k][m]
#pragma unroll
        for (int r = 0; r < (CC*KC)/256; ++r) {
            int idx = r*256 + t;
            int m  = idx >> 5;
            int kk = idx & 31;
            sW[kk*SW_LD + m] = W1[m*CC + k0 + kk];
        }
        // stage X tile (KC x 64)
#pragma unroll
        for (int r = 0; r < (KC*TN)/256; ++r) {
            int idx = r*256 + t;
            int kk = idx >> 6;
            int j  = idx & 63;
            int col = n0 + j;
            float v = 0.f;
            if (col < ncols) v = Xb[(size_t)(k0+kk)*cstride + col];
            sF[kk*TN + j] = v;
        }
        __syncthreads();
#pragma unroll 8
        for (int kk = 0; kk < KC; ++kk) {
            const float4 a0 = *(const float4*)(sW + kk*SW_LD + tm*8);
            const float4 a1 = *(const float4*)(sW + kk*SW_LD + tm*8 + 4);
            const float4 f0 = *(const float4*)(sF + kk*TN + tn*8);
            const float4 f1 = *(const float4*)(sF + kk*TN + tn*8 + 4);
            float av[8] = {a0.x,a0.y,a0.z,a0.w,a1.x,a1.y,a1.z,a1.w};
            float bv[8] = {f0.x,f0.y,f0.z,f0.w,f1.x,f1.y,f1.z,f1.w};
#pragma unroll
            for (int i = 0; i < 8; ++i)
#pragma unroll
                for (int j = 0; j < 8; ++j)
                    acc[i][j] = fmaf(av[i], bv[j], acc[i][j]);
        }
        __syncthreads();
    }

    // epilogue: bias + bn + relu in registers, partial W2 contraction
    float part[3][8];
#pragma unroll
    for (int r = 0; r < 3; ++r)
#pragma unroll
        for (int j = 0; j < 8; ++j) part[r][j] = 0.f;

#pragma unroll
    for (int i = 0; i < 8; ++i) {
        int m = tm*8 + i;
        float scale = __fdiv_rn(Gv[m], __fsqrt_rn(__fadd_rn(Vv[m], 1e-5f)));
        float shift = __fsub_rn(BEv[m], __fmul_rn(Mv[m], scale));
        float w0 = W2[m], w1 = W2[CC + m], w2 = W2[2*CC + m];
        float b1m = B1v[m];
#pragma unroll
        for (int j = 0; j < 8; ++j) {
            float x = __fadd_rn(acc[i][j], b1m);
            float y = __fadd_rn(__fmul_rn(x, scale), shift);
            float h = y > 0.f ? y : 0.f;
            part[0][j] = fmaf(w0, h, part[0][j]);
            part[1][j] = fmaf(w1, h, part[1][j]);
            part[2][j] = fmaf(w2, h, part[2][j]);
        }
    }
#pragma unroll
    for (int r = 0; r < 3; ++r) {
        float4 p0 = {part[r][0], part[r][1], part[r][2], part[r][3]};
        float4 p1 = {part[r][4], part[r][5], part[r][6], part[r][7]};
        *(float4*)(psum + (r*32 + tm)*PS_LD + tn*8)     = p0;
        *(float4*)(psum + (r*32 + tm)*PS_LD + tn*8 + 4) = p1;
    }
    __syncthreads();
    if (t < 192) {
        int r = t >> 6, col = t & 63;
        float s = 0.f;
#pragma unroll
        for (int w = 0; w < 32; ++w) s = __fadd_rn(s, psum[(r*32 + w)*PS_LD + col]);
        float tot = __fadd_rn(s, B2v[r]);
        if (mode == 0) {
            gout[r*64 + col] = tot;
        } else {
            vp[((size_t)b*SS + n0 + col)*3 + r] = tot;
        }
    }
    if (mode == 0) {
        __syncthreads();
        if (t < 64) {
            int n = n0 + t;
            if (n < ncols) {
                float v0 = gout[t], v1 = gout[64 + t], v2 = gout[128 + t];
                o0[(size_t)b*2*ncols + n]         = v0;
                o0[(size_t)b*2*ncols + ncols + n] = v1;
                o1[(size_t)b*ncols + n]           = v2;
                maskp[(size_t)b*ncols + n] = (v2 > 0.1f && v1 > v0) ? 1 : 0;
            }
        }
    }
}

// ---------------------------------------------------------------------------
// Order-preserving stream compaction (1024 threads -> 20 serial tiles)
// ---------------------------------------------------------------------------
__global__ __launch_bounds__(1024) void compact_kernel(
    const unsigned char* __restrict__ maskp, const float* __restrict__ xyz,
    int* __restrict__ cntp, int* __restrict__ corig,
    float* __restrict__ cx, float* __restrict__ cy, float* __restrict__ cz)
{
    const int b = blockIdx.x;
    const int t = threadIdx.x;
    __shared__ int wsum[16];
    __shared__ int running;
    if (t == 0) running = 0;
    __syncthreads();
    const unsigned char* mb = maskp + (size_t)b*NN;
    const size_t bofs = (size_t)b*NN;
    for (int base = 0; base < NN; base += 1024) {
        int i = base + t;
        int m = (i < NN) ? (int)mb[i] : 0;
        unsigned long long bal = __ballot(m != 0);
        int lane = t & 63, w = t >> 6;
        int pre = __popcll(bal & ((1ull << lane) - 1ull));
        if (lane == 0) wsum[w] = __popcll(bal);
        __syncthreads();
        int offs = running;
        for (int ww = 0; ww < w; ++ww) offs += wsum[ww];
        if (m) {
            int pos = offs + pre;
            corig[bofs + pos] = i;
            cx[bofs + pos] = xyz[(bofs + i)*3 + 0];
            cy[bofs + pos] = xyz[(bofs + i)*3 + 1];
            cz[bofs + pos] = xyz[(bofs + i)*3 + 2];
        }
        __syncthreads();
        if (t == 0) {
            int s = 0;
#pragma unroll
            for (int ww = 0; ww < 16; ++ww) s += wsum[ww];
            running += s;
        }
    }
    __syncthreads();
    if (t == 0) cntp[b] = running;
}

// ---------------------------------------------------------------------------
// Masked FPS. Grid = 256 blocks x 256 threads: blocks [0,BB) run the serial
// FPS (4 waves = 1 wave/SIMD). Blocks [BB,256) idle-spin at ~11% duty to keep
// DPM clocks up without power-capping (R3/R4 evidence).
//
// Per iteration: scan slots (value-only max, 9 VALU/candidate), f32 DPP wave
// max, scalar index-locate via per-slot eq-ballots + s_ff1 (tie -> lowest g,
// = np.argmax first-occurrence), SALU-packed u64 key per wave, one barrier,
// 4-key compare, one LDS winner-xyz read.
// ---------------------------------------------------------------------------
static constexpr int FPS_T = 256;
static constexpr int KAMAX = 20;            // max slots/thread (path A)
static constexpr int CAPA  = FPS_T * KAMAX; // 5120

template<int CTRL>
__device__ __forceinline__ unsigned long long dpp_umax(unsigned long long k) {
    int lo = __builtin_amdgcn_update_dpp(0, (int)(unsigned)k,         CTRL, 0xf, 0xf, false);
    int hi = __builtin_amdgcn_update_dpp(0, (int)(unsigned)(k >> 32), CTRL, 0xf, 0xf, false);
    unsigned long long ok = ((unsigned long long)(unsigned)hi << 32) | (unsigned)lo;
    return ok > k ? ok : k;
}

__device__ __forceinline__ unsigned long long wave_umax_dpp(unsigned long long k) {
    k = dpp_umax<0x111>(k);
    k = dpp_umax<0x112>(k);
    k = dpp_umax<0x114>(k);
    k = dpp_umax<0x118>(k);
    k = dpp_umax<0x142>(k);
    k = dpp_umax<0x143>(k);
    return k;
}

template<int CTRL>
__device__ __forceinline__ float dpp_fmax(float v) {
    int o = __builtin_amdgcn_update_dpp(0xFF800000, __float_as_int(v), CTRL, 0xf, 0xf, false);
    return fmaxf(v, __int_as_float(o));
}

__device__ __forceinline__ float wave_fmax_dpp(float v) {
    v = dpp_fmax<0x111>(v);  // row_shr:1
    v = dpp_fmax<0x112>(v);  // row_shr:2
    v = dpp_fmax<0x114>(v);  // row_shr:4
    v = dpp_fmax<0x118>(v);  // row_shr:8
    v = dpp_fmax<0x142>(v);  // row_bcast:15
    v = dpp_fmax<0x143>(v);  // row_bcast:31  -> lane 63 has wave max
    return v;
}

__device__ __forceinline__ unsigned long long pack_key(float v, int i) {
    unsigned long long k = (((unsigned long long)__float_as_uint(v)) << 32)
                         | (unsigned long long)(0xFFFFFFFFu - (unsigned)i);
    return (v == -INFINITY) ? 0ull : k;
}

template<int KAT>
__device__ __forceinline__ void fps_scan_loop(
    int cnt, const float* __restrict__ cxb, const float* __restrict__ cyb,
    const float* __restrict__ czb, const float* __restrict__ sxyz,
    unsigned long long (*swk)[4], int* __restrict__ whist)
{
    const int t = threadIdx.x;
    const int wave = t >> 6, lane = t & 63;

    float X[KAT], Y[KAT], Z[KAT], D[KAT];
#pragma unroll
    for (int j = 0; j < KAT; ++j) {
        int g = t + (j << 8);
        bool v = g < cnt;
        X[j] = v ? cxb[g] : 0.f;
        Y[j] = v ? cyb[g] : 0.f;
        Z[j] = v ? czb[g] : 0.f;
        D[j] = v ? 1e10f : -INFINITY;
    }

    float px = cxb[0], py = cyb[0], pz = czb[0];

    for (int it = 1; it < SS; ++it) {
        // --- scan: update D, track value max only (9 VALU/candidate) ---
        float bv = -INFINITY;
#pragma unroll
        for (int j = 0; j < KAT; ++j) {
            float dx = __fsub_rn(X[j], px);
            float dy = __fsub_rn(Y[j], py);
            float dz = __fsub_rn(Z[j], pz);
            float sxy = __fadd_rn(__fmul_rn(dx,dx), __fmul_rn(dy,dy));
            float d   = __fadd_rn(sxy, __fmul_rn(dz,dz));
            float dn  = fminf(D[j], d);
            D[j] = dn;
            bv = fmaxf(bv, dn);
        }
        // --- wave value max (f32 DPP) + broadcast via readlane ---
        float wv = wave_fmax_dpp(bv);
        float svw = __int_as_float(__builtin_amdgcn_readlane(__float_as_int(wv), 63));
        // --- locate lowest wave-local g with D==svw (np.argmax tie rule) ---
        int gw = 0x7fffffff;
#pragma unroll
        for (int j = KAT-1; j >= 0; --j) {
            unsigned long long m = __ballot(D[j] == svw);
            if (m) gw = (j << 8) + (wave << 6) + (__ffsll((unsigned long long)m) - 1);
        }
        unsigned long long wkey = pack_key(svw, gw);
        int par = it & 1;
        if (lane == 0) swk[par][wave] = wkey;
        __syncthreads();
        const ulonglong2* kp = (const ulonglong2*)&swk[par][0];
        ulonglong2 kA = kp[0], kB = kp[1];
        unsigned long long m0 = kA.x > kA.y ? kA.x : kA.y;
        unsigned long long m1 = kB.x > kB.y ? kB.x : kB.y;
        unsigned long long best = m0 > m1 ? m0 : m1;
        int wi = (int)(0xFFFFFFFFu - (unsigned)(best & 0xFFFFFFFFull));
        float4 w4 = *(const float4*)&sxyz[wi*4];
        px = w4.x; py = w4.y; pz = w4.z;
        if (t == 0) whist[it] = wi;
    }
}

__global__ __launch_bounds__(FPS_T, 1) void fps_kernel(
    const int* __restrict__ cntp, const int* __restrict__ corig,
    const float* __restrict__ cx, const float* __restrict__ cy, const float* __restrict__ cz,
    float* __restrict__ o3, int* __restrict__ oi, int* __restrict__ donep)
{
    const int t = threadIdx.x;

    __shared__ alignas(16) float sxyz[CAPA*4];                // 80 KiB (path B aliases D[] here)
    __shared__ alignas(16) unsigned long long swk[2][4];
    __shared__ int whist[SS];
    __shared__ int sdone;

    if (blockIdx.x >= BB) {
        // ------ clock-warm block: resident but low power (~11% duty) ------
        if (t == 0) sdone = 0;
        __syncthreads();
        float a = 1.0f + (float)t * 1e-6f, bm = 1.0000001f, c = 0.f;
        for (int iter = 0; iter < 20000; ++iter) {
#pragma unroll
            for (int u = 0; u < 16; ++u) c = fmaf(a, bm, c);
            __builtin_amdgcn_s_sleep(8);
            if (t == 0 && (iter & 7) == 0) {
                if (__hip_atomic_load(donep, __ATOMIC_RELAXED, __HIP_MEMORY_SCOPE_AGENT) >= BB)
                    *(volatile int*)&sdone = 1;
            }
            if (*(volatile int*)&sdone) break;
        }
        if (t == 0) donep[4 + (blockIdx.x & 3)] = __float_as_int(c);  // keep c live (scratch)
        return;
    }

    const int b = blockIdx.x;
    const int cnt = cntp[b];
    const size_t bofs = (size_t)b*NN;
    float* o3b = o3 + (size_t)b*SS;
    int*   oib = oi + (size_t)b*SS;
    const int wave = t >> 6, lane = t & 63;

    if (cnt <= 0) {
        for (int s = t; s < SS; s += FPS_T) { o3b[s] = 0.f; oib[s] = 0; }
        if (t == 0) __hip_atomic_fetch_add(donep, 1, __ATOMIC_RELEASE, __HIP_MEMORY_SCOPE_AGENT);
        return;
    }

    if (t == 0) whist[0] = 0;          // first selected = compacted index 0

    if (cnt <= CAPA) {
        // ---------------- Path A: registers + packed LDS xyz mirror ----------------
        for (int g = t; g < cnt; g += FPS_T) {
            float4 w4 = { cx[bofs + g], cy[bofs + g], cz[bofs + g], 0.f };
            *(float4*)&sxyz[g*4] = w4;
        }
        // (first in-loop __syncthreads covers staging visibility before sxyz reads)
        int kat2 = ((cnt + 255) >> 8);
        kat2 = (kat2 + 1) & ~1;        // round up to even: 2..20
        const float* cxb = cx + bofs;
        const float* cyb = cy + bofs;
        const float* czb = cz + bofs;
        switch (kat2) {
            case 2:  fps_scan_loop<2 >(cnt, cxb, cyb, czb, sxyz, swk, whist); break;
            case 4:  fps_scan_loop<4 >(cnt, cxb, cyb, czb, sxyz, swk, whist); break;
            case 6:  fps_scan_loop<6 >(cnt, cxb, cyb, czb, sxyz, swk, whist); break;
            case 8:  fps_scan_loop<8 >(cnt, cxb, cyb, czb, sxyz, swk, whist); break;
            case 10: fps_scan_loop<10>(cnt, cxb, cyb, czb, sxyz, swk, whist); break;
            case 12: fps_scan_loop<12>(cnt, cxb, cyb, czb, sxyz, swk, whist); break;
            case 14: fps_scan_loop<14>(cnt, cxb, cyb, czb, sxyz, swk, whist); break;
            case 16: fps_scan_loop<16>(cnt, cxb, cyb, czb, sxyz, swk, whist); break;
            case 18: fps_scan_loop<18>(cnt, cxb, cyb, czb, sxyz, swk, whist); break;
            default: fps_scan_loop<20>(cnt, cxb, cyb, czb, sxyz, swk, whist); break;
        }
    } else {
        // ---------------- Path B: LDS distances, streamed xyz (fallback) ---------------
        float* Dl = sxyz;
        for (int g = t; g < cnt; g += FPS_T) Dl[g] = 1e10f;
        __syncthreads();

        float px = cx[bofs], py = cy[bofs], pz = cz[bofs];

        for (int it = 1; it < SS; ++it) {
            float bv = -INFINITY; int bi = 0x7fffffff;
            for (int g = t; g < cnt; g += FPS_T) {
                float dx = __fsub_rn(cx[bofs + g], px);
                float dy = __fsub_rn(cy[bofs + g], py);
                float dz = __fsub_rn(cz[bofs + g], pz);
                float d  = __fadd_rn(__fadd_rn(__fmul_rn(dx,dx), __fmul_rn(dy,dy)), __fmul_rn(dz,dz));
                float dn = fminf(Dl[g], d);
                Dl[g] = dn;
                if (dn > bv) { bv = dn; bi = g; }
            }
            unsigned long long key = wave_umax_dpp(pack_key(bv, bi));
            int par = it & 1;
            if (lane == 63) swk[par][wave] = key;
            __syncthreads();
            const ulonglong2* kp = (const ulonglong2*)&swk[par][0];
            ulonglong2 kA = kp[0], kB = kp[1];
            unsigned long long m0 = kA.x > kA.y ? kA.x : kA.y;
            unsigned long long m1 = kB.x > kB.y ? kB.x : kB.y;
            unsigned long long best = m0 > m1 ? m0 : m1;
            int wi = (int)(0xFFFFFFFFu - (unsigned)(best & 0xFFFFFFFFull));
            px = cx[bofs + wi]; py = cy[bofs + wi]; pz = cz[bofs + wi];
            if (t == 0) whist[it] = wi;
        }
    }

    __syncthreads();   // make whist[] fully visible
    for (int s = t; s < SS; s += FPS_T) {
        int wi  = whist[s];
        int org = corig[bofs + wi];
        oib[s] = org;
        o3b[s] = (float)org;
    }
    if (t == 0) __hip_atomic_fetch_add(donep, 1, __ATOMIC_RELEASE, __HIP_MEMORY_SCOPE_AGENT);
}

// ---------------------------------------------------------------------------
// Gathers: 4 samples per thread, int4 index loads, float4 stores
// ---------------------------------------------------------------------------
__global__ __launch_bounds__(256) void gather_kernel(
    const float* __restrict__ xyz, const float* __restrict__ feats,
    const float* __restrict__ grasp, const int* __restrict__ inds,
    float* __restrict__ o2, float* __restrict__ o4, float* __restrict__ o5)
{
    int q = blockIdx.x * 256 + threadIdx.x;   // B*C*S/4 = 262144 threads
    int e = q << 2;
    int b = e >> 18;
    int r = e & ((1 << 18) - 1);
    int c = r >> 10;
    int s = r & 1023;                          // multiple of 4
    int4 i4 = *(const int4*)&inds[(b << 10) + s];
    const float* fb = feats + ((size_t)b*CC + c)*NN;
    float4 v = { fb[i4.x], fb[i4.y], fb[i4.z], fb[i4.w] };
    *(float4*)&o4[e] = v;
    if (c == 0) {
        const float* gb = grasp + (size_t)b*NN;
        float4 g4 = { gb[i4.x], gb[i4.y], gb[i4.z], gb[i4.w] };
        *(float4*)&o5[(b << 10) + s] = g4;
        const float* xb = xyz + (size_t)b*NN*3;
        float o2buf[12];
        int ii[4] = { i4.x, i4.y, i4.z, i4.w };
#pragma unroll
        for (int k = 0; k < 4; ++k) {
            o2buf[k*3+0] = xb[(size_t)ii[k]*3 + 0];
            o2buf[k*3+1] = xb[(size_t)ii[k]*3 + 1];
            o2buf[k*3+2] = xb[(size_t)ii[k]*3 + 2];
        }
        float* dst = o2 + ((size_t)(b << 10) + s)*3;
        *(float4*)&dst[0] = *(float4*)&o2buf[0];
        *(float4*)&dst[4] = *(float4*)&o2buf[4];
        *(float4*)&dst[8] = *(float4*)&o2buf[8];
    }
}

// ---------------------------------------------------------------------------
// top_view argmax + vp_rot
// ---------------------------------------------------------------------------
__global__ __launch_bounds__(256) void view_rot_kernel(
    const float* __restrict__ vp, float* __restrict__ o7, float* __restrict__ o8)
{
    __shared__ float tvx[NV], tvy[NV], tvz[NV];
    int t = threadIdx.x;
    for (int i = t; i < NV; i += 256) {
        double phi = (sqrt(5.0) - 1.0) * 0.5;
        double zd  = (2.0*(double)i + 1.0)/300.0 - 1.0;
        double rr  = sqrt(fmax(1.0 - zd*zd, 0.0));
        double ang = 2.0 * 3.14159265358979323846 * (double)i * phi;
        float fx = (float)(rr * cos(ang));
        float fy = (float)(rr * sin(ang));
        float fz = (float)zd;
        float nr = __fsqrt_rn(__fadd_rn(__fadd_rn(__fmul_rn(fx,fx), __fmul_rn(fy,fy)), __fmul_rn(fz,fz)));
        float dn = fmaxf(nr, 1e-8f);
        tvx[i] = __fdiv_rn(fx, dn);
        tvy[i] = __fdiv_rn(fy, dn);
        tvz[i] = __fdiv_rn(fz, dn);
    }
    __syncthreads();
    int sg = blockIdx.x * 256 + t;   // 0..4095
    float vx = vp[(size_t)sg*3 + 0];
    float vy = vp[(size_t)sg*3 + 1];
    float vz = vp[(size_t)sg*3 + 2];

    float nr = __fsqrt_rn(__fadd_rn(__fadd_rn(__fmul_rn(vx,vx), __fmul_rn(vy,vy)), __fmul_rn(vz,vz)));
    float dn = fmaxf(nr, 1e-8f);
    float ux = __fdiv_rn(vx, dn), uy = __fdiv_rn(vy, dn), uz = __fdiv_rn(vz, dn);
    float best = -INFINITY; int bidx = 0;
    for (int v = 0; v < NV; ++v) {
        float c = __fadd_rn(__fadd_rn(__fmul_rn(ux, tvx[v]), __fmul_rn(uy, tvy[v])), __fmul_rn(uz, tvz[v]));
        if (c > best) { best = c; bidx = v; }
    }
    o7[sg] = (float)bidx;

    // vp_rot: towards = -vp
    float axx = -vx, axy = -vy, axz = -vz;
    float ayx = vy, ayy = -vx, ayz = 0.f;          // ay = [-ax.y, ax.x, 0]
    float s2 = __fadd_rn(__fadd_rn(__fmul_rn(ayx,ayx), __fmul_rn(ayy,ayy)), 0.f);
    if (s2 == 0.f) { ayx = 0.f; ayy = 1.f; ayz = 0.f; }
    float an = __fsqrt_rn(__fadd_rn(__fadd_rn(__fmul_rn(axx,axx), __fmul_rn(axy,axy)), __fmul_rn(axz,axz)));
    float nx0 = __fdiv_rn(axx, an), nx1 = __fdiv_rn(axy, an), nx2 = __fdiv_rn(axz, an);
    float bn2 = __fsqrt_rn(__fadd_rn(__fadd_rn(__fmul_rn(ayx,ayx), __fmul_rn(ayy,ayy)), __fmul_rn(ayz,ayz)));
    float ny0 = __fdiv_rn(ayx, bn2), ny1 = __fdiv_rn(ayy, bn2), ny2 = __fdiv_rn(ayz, bn2);
    float nz0 = __fsub_rn(__fmul_rn(nx1, ny2), __fmul_rn(nx2, ny1));
    float nz1 = __fsub_rn(__fmul_rn(nx2, ny0), __fmul_rn(nx0, ny2));
    float nz2 = __fsub_rn(__fmul_rn(nx0, ny1), __fmul_rn(nx1, ny0));
    size_t o = (size_t)sg * 9;   // rows = (nx_i, ny_i, nz_i)
    o8[o+0] = nx0; o8[o+1] = ny0; o8[o+2] = nz0;
    o8[o+3] = nx1; o8[o+4] = ny1; o8[o+5] = nz1;
    o8[o+6] = nx2; o8[o+7] = ny2; o8[o+8] = nz2;
}

// ---------------------------------------------------------------------------
extern "C" void kernel_launch(void* const* d_in, const int* in_sizes, int n_in,
                              void* d_out, int out_size, void* d_ws, size_t ws_size,
                              hipStream_t stream) {
    const float* xyz   = (const float*)d_in[0];
    const float* feats = (const float*)d_in[1];
    const float* gh_w1 = (const float*)d_in[2];
    const float* gh_b1 = (const float*)d_in[3];
    const float* gh_g  = (const float*)d_in[4];
    const float* gh_be = (const float*)d_in[5];
    const float* gh_m  = (const float*)d_in[6];
    const float* gh_v  = (const float*)d_in[7];
    const float* gh_w2 = (const float*)d_in[8];
    const float* gh_b2 = (const float*)d_in[9];
    const float* c1_w  = (const float*)d_in[10];
    const float* c1_b  = (const float*)d_in[11];
    const float* bn_g  = (const float*)d_in[12];
    const float* bn_b  = (const float*)d_in[13];
    const float* bn_m  = (const float*)d_in[14];
    const float* bn_v  = (const float*)d_in[15];
    const float* c2_w  = (const float*)d_in[16];
    const float* c2_b  = (const float*)d_in[17];

    float* out = (float*)d_out;
    float* o0 = out + O0;
    float* o1 = out + O1;
    float* o2 = out + O2;
    float* o3 = out + O3;
    float* o4 = out + O4;
    float* o5 = out + O5;
    float* o6 = out + O6;
    float* o7 = out + O7;
    float* o8 = out + O8;

    char* ws = (char*)d_ws;
    size_t off = 0;
    auto take = [&](size_t bytes) -> char* {
        char* p = ws + off;
        off = (off + bytes + 255) & ~(size_t)255;
        return p;
    };
    unsigned char* maskp = (unsigned char*)take((size_t)BB*NN);
    int*   cntp  = (int*)take((size_t)BB*4);
    int*   corig = (int*)take((size_t)BB*NN*4);
    float* cx    = (float*)take((size_t)BB*NN*4);
    float* cy    = (float*)take((size_t)BB*NN*4);
    float* cz    = (float*)take((size_t)BB*NN*4);
    int*   indsp = (int*)take((size_t)BB*SS*4);
    int*   donep = (int*)take(64);

    // 1) fused conv+bn+relu+conv over all N points
    gemm_fused<<<dim3((NN + TN - 1)/TN, BB), 256, 0, stream>>>(
        feats, NN, NN, gh_w1, gh_b1, gh_g, gh_be, gh_m, gh_v, gh_w2, gh_b2,
        0, o0, o1, maskp, nullptr);

    // 2) compact masked-in candidates (order-preserving)
    compact_kernel<<<dim3(BB), 1024, 0, stream>>>(maskp, xyz, cntp, corig, cx, cy, cz);

    // 3) sequential FPS over candidates (+ low-duty clock-warm blocks)
    hipMemsetAsync(donep, 0, 4, stream);
    fps_kernel<<<dim3(256), FPS_T, 0, stream>>>(cntp, corig, cx, cy, cz, o3, indsp, donep);

    // 4) gathers
    gather_kernel<<<dim3((BB*CC*SS)/1024), 256, 0, stream>>>(xyz, feats, o1, indsp, o2, o4, o5);

    // 5) second fused conv stack -> vp_xyz
    gemm_fused<<<dim3(SS/TN, BB), 256, 0, stream>>>(
        o4, SS, SS, c1_w, c1_b, bn_g, bn_b, bn_m, bn_v, c2_w, c2_b,
        1, nullptr, nullptr, nullptr, o6);

    // 6) view argmax + rotation matrices
    view_rot_kernel<<<dim3((BB*SS)/256), 256, 0, stream>>>(o6, o7, o8);
}

// Round 6
// 1144.541 us; speedup vs baseline: 2.7868x; 1.0535x over previous
//
#include <hip/hip_runtime.h>
#include <hip/hip_bf16.h>
#include <math.h>

static constexpr int BB = 4;
static constexpr int NN = 20000;
static constexpr int CC = 256;
static constexpr int SS = 1024;   // NUM_SAMPLE
static constexpr int NV = 300;    // NUM_VIEW

// output offsets (floats) in d_out, concatenated in reference return order
static constexpr size_t O0 = 0;                     // objectness (B,2,N)
static constexpr size_t O1 = O0 + (size_t)BB*2*NN;  // graspness (B,N)
static constexpr size_t O2 = O1 + (size_t)BB*NN;    // graspable_xyz (B,S,3)
static constexpr size_t O3 = O2 + (size_t)BB*SS*3;  // graspable_inds (B,S) as float
static constexpr size_t O4 = O3 + (size_t)BB*SS;    // graspable_features (B,C,S)
static constexpr size_t O5 = O4 + (size_t)BB*CC*SS; // fp2_graspness (B,S)
static constexpr size_t O6 = O5 + (size_t)BB*SS;    // vp_xyz (B,S,3)
static constexpr size_t O7 = O6 + (size_t)BB*SS*3;  // top_view_inds (B,S) as float
static constexpr size_t O8 = O7 + (size_t)BB*SS;    // vp_rot (B,S,3,3)

typedef float v2f __attribute__((ext_vector_type(2)));

// ---------------------------------------------------------------------------
// Fused GEMM: out3ch = W2(3x256) @ relu(bn(W1(256x256) @ X + b1)) + b2
// mode 0: write objectness/graspness/mask   mode 1: write vp_xyz (B,S,3)
// ---------------------------------------------------------------------------
static constexpr int TN = 64;     // columns per block
static constexpr int KC = 32;     // k-chunk
static constexpr int SW_LD = 260; // padded LDS row for sW[k][m]
static constexpr int PS_LD = 68;  // padded LDS row for psum

__global__ __launch_bounds__(256, 2) void gemm_fused(
    const float* __restrict__ X, int ncols, int cstride,
    const float* __restrict__ W1, const float* __restrict__ B1v,
    const float* __restrict__ Gv, const float* __restrict__ BEv,
    const float* __restrict__ Mv, const float* __restrict__ Vv,
    const float* __restrict__ W2, const float* __restrict__ B2v,
    int mode, float* __restrict__ o0, float* __restrict__ o1,
    unsigned char* __restrict__ maskp, float* __restrict__ vp)
{
    __shared__ alignas(16) char smem_raw[KC*SW_LD*4 + KC*TN*4]; // 41472 B (phase2 aliases)
    float* sW   = (float*)smem_raw;                       // [KC][SW_LD]
    float* sF   = (float*)(smem_raw + KC*SW_LD*4);        // [KC][TN]
    float* psum = (float*)smem_raw;                       // [3][32][PS_LD] = 26112 B
    float* gout = (float*)(smem_raw + 3*32*PS_LD*4);      // [3][64]

    const int t  = threadIdx.x;
    const int b  = blockIdx.y;
    const int n0 = blockIdx.x * TN;
    const int tm = t & 31;   // 32 groups along M (8 rows each)
    const int tn = t >> 5;   // 8 groups along N (8 cols each)

    const float* Xb = X + (size_t)b * CC * cstride;

    float acc[8][8];
#pragma unroll
    for (int i = 0; i < 8; ++i)
#pragma unroll
        for (int j = 0; j < 8; ++j) acc[i][j] = 0.f;

    for (int k0 = 0; k0 < CC; k0 += KC) {
        // stage W1 tile (256 x KC), transposed into sW[k][m]
#pragma unroll
        for (int r = 0; r < (CC*KC)/256; ++r) {
            int idx = r*256 + t;
            int m  = idx >> 5;
            int kk = idx & 31;
            sW[kk*SW_LD + m] = W1[m*CC + k0 + kk];
        }
        // stage X tile (KC x 64)
#pragma unroll
        for (int r = 0; r < (KC*TN)/256; ++r) {
            int idx = r*256 + t;
            int kk = idx >> 6;
            int j  = idx & 63;
            int col = n0 + j;
            float v = 0.f;
            if (col < ncols) v = Xb[(size_t)(k0+kk)*cstride + col];
            sF[kk*TN + j] = v;
        }
        __syncthreads();
#pragma unroll 8
        for (int kk = 0; kk < KC; ++kk) {
            const float4 a0 = *(const float4*)(sW + kk*SW_LD + tm*8);
            const float4 a1 = *(const float4*)(sW + kk*SW_LD + tm*8 + 4);
            const float4 f0 = *(const float4*)(sF + kk*TN + tn*8);
            const float4 f1 = *(const float4*)(sF + kk*TN + tn*8 + 4);
            float av[8] = {a0.x,a0.y,a0.z,a0.w,a1.x,a1.y,a1.z,a1.w};
            float bv[8] = {f0.x,f0.y,f0.z,f0.w,f1.x,f1.y,f1.z,f1.w};
#pragma unroll
            for (int i = 0; i < 8; ++i)
#pragma unroll
                for (int j = 0; j < 8; ++j)
                    acc[i][j] = fmaf(av[i], bv[j], acc[i][j]);
        }
        __syncthreads();
    }

    // epilogue: bias + bn + relu in registers, partial W2 contraction
    float part[3][8];
#pragma unroll
    for (int r = 0; r < 3; ++r)
#pragma unroll
        for (int j = 0; j < 8; ++j) part[r][j] = 0.f;

#pragma unroll
    for (int i = 0; i < 8; ++i) {
        int m = tm*8 + i;
        float scale = __fdiv_rn(Gv[m], __fsqrt_rn(__fadd_rn(Vv[m], 1e-5f)));
        float shift = __fsub_rn(BEv[m], __fmul_rn(Mv[m], scale));
        float w0 = W2[m], w1 = W2[CC + m], w2 = W2[2*CC + m];
        float b1m = B1v[m];
#pragma unroll
        for (int j = 0; j < 8; ++j) {
            float x = __fadd_rn(acc[i][j], b1m);
            float y = __fadd_rn(__fmul_rn(x, scale), shift);
            float h = y > 0.f ? y : 0.f;
            part[0][j] = fmaf(w0, h, part[0][j]);
            part[1][j] = fmaf(w1, h, part[1][j]);
            part[2][j] = fmaf(w2, h, part[2][j]);
        }
    }
#pragma unroll
    for (int r = 0; r < 3; ++r) {
        float4 p0 = {part[r][0], part[r][1], part[r][2], part[r][3]};
        float4 p1 = {part[r][4], part[r][5], part[r][6], part[r][7]};
        *(float4*)(psum + (r*32 + tm)*PS_LD + tn*8)     = p0;
        *(float4*)(psum + (r*32 + tm)*PS_LD + tn*8 + 4) = p1;
    }
    __syncthreads();
    if (t < 192) {
        int r = t >> 6, col = t & 63;
        float s = 0.f;
#pragma unroll
        for (int w = 0; w < 32; ++w) s = __fadd_rn(s, psum[(r*32 + w)*PS_LD + col]);
        float tot = __fadd_rn(s, B2v[r]);
        if (mode == 0) {
            gout[r*64 + col] = tot;
        } else {
            vp[((size_t)b*SS + n0 + col)*3 + r] = tot;
        }
    }
    if (mode == 0) {
        __syncthreads();
        if (t < 64) {
            int n = n0 + t;
            if (n < ncols) {
                float v0 = gout[t], v1 = gout[64 + t], v2 = gout[128 + t];
                o0[(size_t)b*2*ncols + n]         = v0;
                o0[(size_t)b*2*ncols + ncols + n] = v1;
                o1[(size_t)b*ncols + n]           = v2;
                maskp[(size_t)b*ncols + n] = (v2 > 0.1f && v1 > v0) ? 1 : 0;
            }
        }
    }
}

// ---------------------------------------------------------------------------
// Order-preserving stream compaction (1024 threads -> 20 serial tiles)
// ---------------------------------------------------------------------------
__global__ __launch_bounds__(1024) void compact_kernel(
    const unsigned char* __restrict__ maskp, const float* __restrict__ xyz,
    int* __restrict__ cntp, int* __restrict__ corig,
    float* __restrict__ cx, float* __restrict__ cy, float* __restrict__ cz)
{
    const int b = blockIdx.x;
    const int t = threadIdx.x;
    __shared__ int wsum[16];
    __shared__ int running;
    if (t == 0) running = 0;
    __syncthreads();
    const unsigned char* mb = maskp + (size_t)b*NN;
    const size_t bofs = (size_t)b*NN;
    for (int base = 0; base < NN; base += 1024) {
        int i = base + t;
        int m = (i < NN) ? (int)mb[i] : 0;
        unsigned long long bal = __ballot(m != 0);
        int lane = t & 63, w = t >> 6;
        int pre = __popcll(bal & ((1ull << lane) - 1ull));
        if (lane == 0) wsum[w] = __popcll(bal);
        __syncthreads();
        int offs = running;
        for (int ww = 0; ww < w; ++ww) offs += wsum[ww];
        if (m) {
            int pos = offs + pre;
            corig[bofs + pos] = i;
            cx[bofs + pos] = xyz[(bofs + i)*3 + 0];
            cy[bofs + pos] = xyz[(bofs + i)*3 + 1];
            cz[bofs + pos] = xyz[(bofs + i)*3 + 2];
        }
        __syncthreads();
        if (t == 0) {
            int s = 0;
#pragma unroll
            for (int ww = 0; ww < 16; ++ww) s += wsum[ww];
            running += s;
        }
    }
    __syncthreads();
    if (t == 0) cntp[b] = running;
}

// ---------------------------------------------------------------------------
// Masked FPS. Grid = 256 blocks x 256 threads: blocks [0,BB) run the serial
// FPS (4 waves = 1 wave/SIMD). Blocks [BB,256) idle-spin at ~6% duty (R4's
// proven clock-friendly point; 100% duty regressed in R3 -> power/clock cap).
//
// R6: scan processes slot PAIRS via ext_vector f32x2 (v_pk_mul/add candidates)
// under `clang fp contract(off)` so each component stays exact RN mul/add in
// np's order ((dx^2+dy^2)+dz^2). Index tracked in-scan via cndmask (R4
// semantics: strict >, ascending j then component -> lowest-g first-max).
// Wave reduce: u64 key DPP max; cross-wave via 4 LDS keys (R4).
// ---------------------------------------------------------------------------
static constexpr int FPS_T = 256;
static constexpr int KAMAX = 20;            // max slots/thread (path A)
static constexpr int CAPA  = FPS_T * KAMAX; // 5120

template<int CTRL>
__device__ __forceinline__ unsigned long long dpp_umax(unsigned long long k) {
    int lo = __builtin_amdgcn_update_dpp(0, (int)(unsigned)k,         CTRL, 0xf, 0xf, false);
    int hi = __builtin_amdgcn_update_dpp(0, (int)(unsigned)(k >> 32), CTRL, 0xf, 0xf, false);
    unsigned long long ok = ((unsigned long long)(unsigned)hi << 32) | (unsigned)lo;
    return ok > k ? ok : k;
}

__device__ __forceinline__ unsigned long long wave_umax_dpp(unsigned long long k) {
    k = dpp_umax<0x111>(k);  // row_shr:1
    k = dpp_umax<0x112>(k);  // row_shr:2
    k = dpp_umax<0x114>(k);  // row_shr:4
    k = dpp_umax<0x118>(k);  // row_shr:8
    k = dpp_umax<0x142>(k);  // row_bcast:15
    k = dpp_umax<0x143>(k);  // row_bcast:31  -> lane 63 has wave max
    return k;
}

__device__ __forceinline__ unsigned long long pack_key(float v, int i) {
    unsigned long long k = (((unsigned long long)__float_as_uint(v)) << 32)
                         | (unsigned long long)(0xFFFFFFFFu - (unsigned)i);
    return (v == -INFINITY) ? 0ull : k;
}

template<int KP>   // pairs of slots per thread
__device__ __forceinline__ void fps_scan_loop(
    int cnt, const float* __restrict__ cxb, const float* __restrict__ cyb,
    const float* __restrict__ czb, const float* __restrict__ sxyz,
    unsigned long long (*swk)[4], int* __restrict__ whist)
{
#pragma clang fp contract(off)
    const int t = threadIdx.x;
    const int wave = t >> 6, lane = t & 63;

    v2f X2[KP], Y2[KP], Z2[KP], D2[KP];
#pragma unroll
    for (int jp = 0; jp < KP; ++jp) {
        int g0 = t + ((2*jp) << 8);
        int g1 = g0 + 256;
        bool v0 = g0 < cnt, v1 = g1 < cnt;
        X2[jp][0] = v0 ? cxb[g0] : 0.f;  X2[jp][1] = v1 ? cxb[g1] : 0.f;
        Y2[jp][0] = v0 ? cyb[g0] : 0.f;  Y2[jp][1] = v1 ? cyb[g1] : 0.f;
        Z2[jp][0] = v0 ? czb[g0] : 0.f;  Z2[jp][1] = v1 ? czb[g1] : 0.f;
        D2[jp][0] = v0 ? 1e10f : -INFINITY;
        D2[jp][1] = v1 ? 1e10f : -INFINITY;
    }

    float px = cxb[0], py = cyb[0], pz = czb[0];

    for (int it = 1; it < SS; ++it) {
        float bv = -INFINITY; int bi = 0x7fffffff;
#pragma unroll
        for (int jp = 0; jp < KP; ++jp) {
            v2f dx = X2[jp] - px;           // packed RN sub
            v2f dy = Y2[jp] - py;
            v2f dz = Z2[jp] - pz;
            v2f xx = dx*dx, yy = dy*dy;     // packed RN mul (contract off)
            v2f sxy = xx + yy;              // packed RN add
            v2f zz = dz*dz;
            v2f dd = sxy + zz;              // ((dx^2+dy^2)+dz^2), np order
            float dn0 = fminf(D2[jp][0], dd[0]);
            float dn1 = fminf(D2[jp][1], dd[1]);
            D2[jp][0] = dn0;
            D2[jp][1] = dn1;
            if (dn0 > bv) { bv = dn0; bi = t + ((2*jp)   << 8); }
            if (dn1 > bv) { bv = dn1; bi = t + ((2*jp+1) << 8); }
        }
        unsigned long long key = wave_umax_dpp(pack_key(bv, bi));
        int par = it & 1;
        if (lane == 63) swk[par][wave] = key;
        __syncthreads();
        const ulonglong2* kp = (const ulonglong2*)&swk[par][0];
        ulonglong2 kA = kp[0], kB = kp[1];
        unsigned long long m0 = kA.x > kA.y ? kA.x : kA.y;
        unsigned long long m1 = kB.x > kB.y ? kB.x : kB.y;
        unsigned long long best = m0 > m1 ? m0 : m1;
        int wi = (int)(0xFFFFFFFFu - (unsigned)(best & 0xFFFFFFFFull));
        float4 w4 = *(const float4*)&sxyz[wi*4];
        px = w4.x; py = w4.y; pz = w4.z;
        if (t == 0) whist[it] = wi;
    }
}

__global__ __launch_bounds__(FPS_T, 1) void fps_kernel(
    const int* __restrict__ cntp, const int* __restrict__ corig,
    const float* __restrict__ cx, const float* __restrict__ cy, const float* __restrict__ cz,
    float* __restrict__ o3, int* __restrict__ oi, int* __restrict__ donep)
{
    const int t = threadIdx.x;

    __shared__ alignas(16) float sxyz[CAPA*4];                // 80 KiB (path B aliases D[] here)
    __shared__ alignas(16) unsigned long long swk[2][4];
    __shared__ int whist[SS];
    __shared__ int sdone;

    if (blockIdx.x >= BB) {
        // ------ clock-warm block: resident but low power (~6% duty, R4) ------
        if (t == 0) sdone = 0;
        __syncthreads();
        float a = 1.0f + (float)t * 1e-6f, bm = 1.0000001f, c = 0.f;
        for (int iter = 0; iter < 20000; ++iter) {
#pragma unroll
            for (int u = 0; u < 16; ++u) c = fmaf(a, bm, c);
            __builtin_amdgcn_s_sleep(8);
            if (t == 0 && (iter & 7) == 0) {
                if (__hip_atomic_load(donep, __ATOMIC_RELAXED, __HIP_MEMORY_SCOPE_AGENT) >= BB)
                    *(volatile int*)&sdone = 1;
            }
            if (*(volatile int*)&sdone) break;
        }
        if (t == 0) donep[4 + (blockIdx.x & 3)] = __float_as_int(c);  // keep c live (scratch)
        return;
    }

    const int b = blockIdx.x;
    const int cnt = cntp[b];
    const size_t bofs = (size_t)b*NN;
    float* o3b = o3 + (size_t)b*SS;
    int*   oib = oi + (size_t)b*SS;
    const int wave = t >> 6, lane = t & 63;

    if (cnt <= 0) {
        for (int s = t; s < SS; s += FPS_T) { o3b[s] = 0.f; oib[s] = 0; }
        if (t == 0) __hip_atomic_fetch_add(donep, 1, __ATOMIC_RELEASE, __HIP_MEMORY_SCOPE_AGENT);
        return;
    }

    if (t == 0) whist[0] = 0;          // first selected = compacted index 0

    if (cnt <= CAPA) {
        // ---------------- Path A: registers + packed LDS xyz mirror ----------------
        for (int g = t; g < cnt; g += FPS_T) {
            float4 w4 = { cx[bofs + g], cy[bofs + g], cz[bofs + g], 0.f };
            *(float4*)&sxyz[g*4] = w4;
        }
        // (first in-loop __syncthreads covers staging visibility before sxyz reads)
        int kat2 = ((cnt + 255) >> 8);
        kat2 = (kat2 + 1) & ~1;        // round up to even: 2..20
        int kpn = kat2 >> 1;           // pairs: 1..10
        const float* cxb = cx + bofs;
        const float* cyb = cy + bofs;
        const float* czb = cz + bofs;
        switch (kpn) {
            case 1:  fps_scan_loop<1 >(cnt, cxb, cyb, czb, sxyz, swk, whist); break;
            case 2:  fps_scan_loop<2 >(cnt, cxb, cyb, czb, sxyz, swk, whist); break;
            case 3:  fps_scan_loop<3 >(cnt, cxb, cyb, czb, sxyz, swk, whist); break;
            case 4:  fps_scan_loop<4 >(cnt, cxb, cyb, czb, sxyz, swk, whist); break;
            case 5:  fps_scan_loop<5 >(cnt, cxb, cyb, czb, sxyz, swk, whist); break;
            case 6:  fps_scan_loop<6 >(cnt, cxb, cyb, czb, sxyz, swk, whist); break;
            case 7:  fps_scan_loop<7 >(cnt, cxb, cyb, czb, sxyz, swk, whist); break;
            case 8:  fps_scan_loop<8 >(cnt, cxb, cyb, czb, sxyz, swk, whist); break;
            case 9:  fps_scan_loop<9 >(cnt, cxb, cyb, czb, sxyz, swk, whist); break;
            default: fps_scan_loop<10>(cnt, cxb, cyb, czb, sxyz, swk, whist); break;
        }
    } else {
        // ---------------- Path B: LDS distances, streamed xyz (fallback) ---------------
        float* Dl = sxyz;
        for (int g = t; g < cnt; g += FPS_T) Dl[g] = 1e10f;
        __syncthreads();

        float px = cx[bofs], py = cy[bofs], pz = cz[bofs];

        for (int it = 1; it < SS; ++it) {
            float bv = -INFINITY; int bi = 0x7fffffff;
            for (int g = t; g < cnt; g += FPS_T) {
                float dx = __fsub_rn(cx[bofs + g], px);
                float dy = __fsub_rn(cy[bofs + g], py);
                float dz = __fsub_rn(cz[bofs + g], pz);
                float d  = __fadd_rn(__fadd_rn(__fmul_rn(dx,dx), __fmul_rn(dy,dy)), __fmul_rn(dz,dz));
                float dn = fminf(Dl[g], d);
                Dl[g] = dn;
                if (dn > bv) { bv = dn; bi = g; }
            }
            unsigned long long key = wave_umax_dpp(pack_key(bv, bi));
            int par = it & 1;
            if (lane == 63) swk[par][wave] = key;
            __syncthreads();
            const ulonglong2* kp = (const ulonglong2*)&swk[par][0];
            ulonglong2 kA = kp[0], kB = kp[1];
            unsigned long long m0 = kA.x > kA.y ? kA.x : kA.y;
            unsigned long long m1 = kB.x > kB.y ? kB.x : kB.y;
            unsigned long long best = m0 > m1 ? m0 : m1;
            int wi = (int)(0xFFFFFFFFu - (unsigned)(best & 0xFFFFFFFFull));
            px = cx[bofs + wi]; py = cy[bofs + wi]; pz = cz[bofs + wi];
            if (t == 0) whist[it] = wi;
        }
    }

    __syncthreads();   // make whist[] fully visible
    for (int s = t; s < SS; s += FPS_T) {
        int wi  = whist[s];
        int org = corig[bofs + wi];
        oib[s] = org;
        o3b[s] = (float)org;
    }
    if (t == 0) __hip_atomic_fetch_add(donep, 1, __ATOMIC_RELEASE, __HIP_MEMORY_SCOPE_AGENT);
}

// ---------------------------------------------------------------------------
// Gathers: 4 samples per thread, int4 index loads, float4 stores
// ---------------------------------------------------------------------------
__global__ __launch_bounds__(256) void gather_kernel(
    const float* __restrict__ xyz, const float* __restrict__ feats,
    const float* __restrict__ grasp, const int* __restrict__ inds,
    float* __restrict__ o2, float* __restrict__ o4, float* __restrict__ o5)
{
    int q = blockIdx.x * 256 + threadIdx.x;   // B*C*S/4 = 262144 threads
    int e = q << 2;
    int b = e >> 18;
    int r = e & ((1 << 18) - 1);
    int c = r >> 10;
    int s = r & 1023;                          // multiple of 4
    int4 i4 = *(const int4*)&inds[(b << 10) + s];
    const float* fb = feats + ((size_t)b*CC + c)*NN;
    float4 v = { fb[i4.x], fb[i4.y], fb[i4.z], fb[i4.w] };
    *(float4*)&o4[e] = v;
    if (c == 0) {
        const float* gb = grasp + (size_t)b*NN;
        float4 g4 = { gb[i4.x], gb[i4.y], gb[i4.z], gb[i4.w] };
        *(float4*)&o5[(b << 10) + s] = g4;
        const float* xb = xyz + (size_t)b*NN*3;
        float o2buf[12];
        int ii[4] = { i4.x, i4.y, i4.z, i4.w };
#pragma unroll
        for (int k = 0; k < 4; ++k) {
            o2buf[k*3+0] = xb[(size_t)ii[k]*3 + 0];
            o2buf[k*3+1] = xb[(size_t)ii[k]*3 + 1];
            o2buf[k*3+2] = xb[(size_t)ii[k]*3 + 2];
        }
        float* dst = o2 + ((size_t)(b << 10) + s)*3;
        *(float4*)&dst[0] = *(float4*)&o2buf[0];
        *(float4*)&dst[4] = *(float4*)&o2buf[4];
        *(float4*)&dst[8] = *(float4*)&o2buf[8];
    }
}

// ---------------------------------------------------------------------------
// top_view argmax + vp_rot
// ---------------------------------------------------------------------------
__global__ __launch_bounds__(256) void view_rot_kernel(
    const float* __restrict__ vp, float* __restrict__ o7, float* __restrict__ o8)
{
    __shared__ float tvx[NV], tvy[NV], tvz[NV];
    int t = threadIdx.x;
    for (int i = t; i < NV; i += 256) {
        double phi = (sqrt(5.0) - 1.0) * 0.5;
        double zd  = (2.0*(double)i + 1.0)/300.0 - 1.0;
        double rr  = sqrt(fmax(1.0 - zd*zd, 0.0));
        double ang = 2.0 * 3.14159265358979323846 * (double)i * phi;
        float fx = (float)(rr * cos(ang));
        float fy = (float)(rr * sin(ang));
        float fz = (float)zd;
        float nr = __fsqrt_rn(__fadd_rn(__fadd_rn(__fmul_rn(fx,fx), __fmul_rn(fy,fy)), __fmul_rn(fz,fz)));
        float dn = fmaxf(nr, 1e-8f);
        tvx[i] = __fdiv_rn(fx, dn);
        tvy[i] = __fdiv_rn(fy, dn);
        tvz[i] = __fdiv_rn(fz, dn);
    }
    __syncthreads();
    int sg = blockIdx.x * 256 + t;   // 0..4095
    float vx = vp[(size_t)sg*3 + 0];
    float vy = vp[(size_t)sg*3 + 1];
    float vz = vp[(size_t)sg*3 + 2];

    float nr = __fsqrt_rn(__fadd_rn(__fadd_rn(__fmul_rn(vx,vx), __fmul_rn(vy,vy)), __fmul_rn(vz,vz)));
    float dn = fmaxf(nr, 1e-8f);
    float ux = __fdiv_rn(vx, dn), uy = __fdiv_rn(vy, dn), uz = __fdiv_rn(vz, dn);
    float best = -INFINITY; int bidx = 0;
    for (int v = 0; v < NV; ++v) {
        float c = __fadd_rn(__fadd_rn(__fmul_rn(ux, tvx[v]), __fmul_rn(uy, tvy[v])), __fmul_rn(uz, tvz[v]));
        if (c > best) { best = c; bidx = v; }
    }
    o7[sg] = (float)bidx;

    // vp_rot: towards = -vp
    float axx = -vx, axy = -vy, axz = -vz;
    float ayx = vy, ayy = -vx, ayz = 0.f;          // ay = [-ax.y, ax.x, 0]
    float s2 = __fadd_rn(__fadd_rn(__fmul_rn(ayx,ayx), __fmul_rn(ayy,ayy)), 0.f);
    if (s2 == 0.f) { ayx = 0.f; ayy = 1.f; ayz = 0.f; }
    float an = __fsqrt_rn(__fadd_rn(__fadd_rn(__fmul_rn(axx,axx), __fmul_rn(axy,axy)), __fmul_rn(axz,axz)));
    float nx0 = __fdiv_rn(axx, an), nx1 = __fdiv_rn(axy, an), nx2 = __fdiv_rn(axz, an);
    float bn2 = __fsqrt_rn(__fadd_rn(__fadd_rn(__fmul_rn(ayx,ayx), __fmul_rn(ayy,ayy)), __fmul_rn(ayz,ayz)));
    float ny0 = __fdiv_rn(ayx, bn2), ny1 = __fdiv_rn(ayy, bn2), ny2 = __fdiv_rn(ayz, bn2);
    float nz0 = __fsub_rn(__fmul_rn(nx1, ny2), __fmul_rn(nx2, ny1));
    float nz1 = __fsub_rn(__fmul_rn(nx2, ny0), __fmul_rn(nx0, ny2));
    float nz2 = __fsub_rn(__fmul_rn(nx0, ny1), __fmul_rn(nx1, ny0));
    size_t o = (size_t)sg * 9;   // rows = (nx_i, ny_i, nz_i)
    o8[o+0] = nx0; o8[o+1] = ny0; o8[o+2] = nz0;
    o8[o+3] = nx1; o8[o+4] = ny1; o8[o+5] = nz1;
    o8[o+6] = nx2; o8[o+7] = ny2; o8[o+8] = nz2;
}

// ---------------------------------------------------------------------------
extern "C" void kernel_launch(void* const* d_in, const int* in_sizes, int n_in,
                              void* d_out, int out_size, void* d_ws, size_t ws_size,
                              hipStream_t stream) {
    const float* xyz   = (const float*)d_in[0];
    const float* feats = (const float*)d_in[1];
    const float* gh_w1 = (const float*)d_in[2];
    const float* gh_b1 = (const float*)d_in[3];
    const float* gh_g  = (const float*)d_in[4];
    const float* gh_be = (const float*)d_in[5];
    const float* gh_m  = (const float*)d_in[6];
    const float* gh_v  = (const float*)d_in[7];
    const float* gh_w2 = (const float*)d_in[8];
    const float* gh_b2 = (const float*)d_in[9];
    const float* c1_w  = (const float*)d_in[10];
    const float* c1_b  = (const float*)d_in[11];
    const float* bn_g  = (const float*)d_in[12];
    const float* bn_b  = (const float*)d_in[13];
    const float* bn_m  = (const float*)d_in[14];
    const float* bn_v  = (const float*)d_in[15];
    const float* c2_w  = (const float*)d_in[16];
    const float* c2_b  = (const float*)d_in[17];

    float* out = (float*)d_out;
    float* o0 = out + O0;
    float* o1 = out + O1;
    float* o2 = out + O2;
    float* o3 = out + O3;
    float* o4 = out + O4;
    float* o5 = out + O5;
    float* o6 = out + O6;
    float* o7 = out + O7;
    float* o8 = out + O8;

    char* ws = (char*)d_ws;
    size_t off = 0;
    auto take = [&](size_t bytes) -> char* {
        char* p = ws + off;
        off = (off + bytes + 255) & ~(size_t)255;
        return p;
    };
    unsigned char* maskp = (unsigned char*)take((size_t)BB*NN);
    int*   cntp  = (int*)take((size_t)BB*4);
    int*   corig = (int*)take((size_t)BB*NN*4);
    float* cx    = (float*)take((size_t)BB*NN*4);
    float* cy    = (float*)take((size_t)BB*NN*4);
    float* cz    = (float*)take((size_t)BB*NN*4);
    int*   indsp = (int*)take((size_t)BB*SS*4);
    int*   donep = (int*)take(64);

    // 1) fused conv+bn+relu+conv over all N points
    gemm_fused<<<dim3((NN + TN - 1)/TN, BB), 256, 0, stream>>>(
        feats, NN, NN, gh_w1, gh_b1, gh_g, gh_be, gh_m, gh_v, gh_w2, gh_b2,
        0, o0, o1, maskp, nullptr);

    // 2) compact masked-in candidates (order-preserving)
    compact_kernel<<<dim3(BB), 1024, 0, stream>>>(maskp, xyz, cntp, corig, cx, cy, cz);

    // 3) sequential FPS over candidates (+ low-duty clock-warm blocks)
    hipMemsetAsync(donep, 0, 4, stream);
    fps_kernel<<<dim3(256), FPS_T, 0, stream>>>(cntp, corig, cx, cy, cz, o3, indsp, donep);

    // 4) gathers
    gather_kernel<<<dim3((BB*CC*SS)/1024), 256, 0, stream>>>(xyz, feats, o1, indsp, o2, o4, o5);

    // 5) second fused conv stack -> vp_xyz
    gemm_fused<<<dim3(SS/TN, BB), 256, 0, stream>>>(
        o4, SS, SS, c1_w, c1_b, bn_g, bn_b, bn_m, bn_v, c2_w, c2_b,
        1, nullptr, nullptr, nullptr, o6);

    // 6) view argmax + rotation matrices
    view_rot_kernel<<<dim3((BB*SS)/256), 256, 0, stream>>>(o6, o7, o8);
}

// Round 7
// 1098.903 us; speedup vs baseline: 2.9025x; 1.0415x over previous
//
#include <hip/hip_runtime.h>
#include <hip/hip_bf16.h>
#include <math.h>

static constexpr int BB = 4;
static constexpr int NN = 20000;
static constexpr int CC = 256;
static constexpr int SS = 1024;   // NUM_SAMPLE
static constexpr int NV = 300;    // NUM_VIEW

// output offsets (floats) in d_out, concatenated in reference return order
static constexpr size_t O0 = 0;                     // objectness (B,2,N)
static constexpr size_t O1 = O0 + (size_t)BB*2*NN;  // graspness (B,N)
static constexpr size_t O2 = O1 + (size_t)BB*NN;    // graspable_xyz (B,S,3)
static constexpr size_t O3 = O2 + (size_t)BB*SS*3;  // graspable_inds (B,S) as float
static constexpr size_t O4 = O3 + (size_t)BB*SS;    // graspable_features (B,C,S)
static constexpr size_t O5 = O4 + (size_t)BB*CC*SS; // fp2_graspness (B,S)
static constexpr size_t O6 = O5 + (size_t)BB*SS;    // vp_xyz (B,S,3)
static constexpr size_t O7 = O6 + (size_t)BB*SS*3;  // top_view_inds (B,S) as float
static constexpr size_t O8 = O7 + (size_t)BB*SS;    // vp_rot (B,S,3,3)

typedef float v2f __attribute__((ext_vector_type(2)));

// ---------------------------------------------------------------------------
// GEMM1: out3ch = W2(3x256) @ relu(bn(W1(256x256) @ X + b1)) + b2
// writes objectness (o0) + graspness (o1)
// ---------------------------------------------------------------------------
static constexpr int TN = 64;     // columns per block
static constexpr int KC = 32;     // k-chunk
static constexpr int SW_LD = 260; // padded LDS row for sW[k][m]
static constexpr int PS_LD = 68;  // padded LDS row for psum

__global__ __launch_bounds__(256, 2) void gemm_fused(
    const float* __restrict__ X,
    const float* __restrict__ W1, const float* __restrict__ B1v,
    const float* __restrict__ Gv, const float* __restrict__ BEv,
    const float* __restrict__ Mv, const float* __restrict__ Vv,
    const float* __restrict__ W2, const float* __restrict__ B2v,
    float* __restrict__ o0, float* __restrict__ o1)
{
    __shared__ alignas(16) char smem_raw[KC*SW_LD*4 + KC*TN*4]; // 41472 B
    float* sW   = (float*)smem_raw;                       // [KC][SW_LD]
    float* sF   = (float*)(smem_raw + KC*SW_LD*4);        // [KC][TN]
    float* psum = (float*)smem_raw;                       // [3][32][PS_LD]
    float* gout = (float*)(smem_raw + 3*32*PS_LD*4);      // [3][64]

    const int t  = threadIdx.x;
    const int b  = blockIdx.y;
    const int n0 = blockIdx.x * TN;
    const int tm = t & 31;
    const int tn = t >> 5;

    const float* Xb = X + (size_t)b * CC * NN;

    float acc[8][8];
#pragma unroll
    for (int i = 0; i < 8; ++i)
#pragma unroll
        for (int j = 0; j < 8; ++j) acc[i][j] = 0.f;

    for (int k0 = 0; k0 < CC; k0 += KC) {
#pragma unroll
        for (int r = 0; r < (CC*KC)/256; ++r) {
            int idx = r*256 + t;
            int m  = idx >> 5;
            int kk = idx & 31;
            sW[kk*SW_LD + m] = W1[m*CC + k0 + kk];
        }
#pragma unroll
        for (int r = 0; r < (KC*TN)/256; ++r) {
            int idx = r*256 + t;
            int kk = idx >> 6;
            int j  = idx & 63;
            int col = n0 + j;
            float v = 0.f;
            if (col < NN) v = Xb[(size_t)(k0+kk)*NN + col];
            sF[kk*TN + j] = v;
        }
        __syncthreads();
#pragma unroll 8
        for (int kk = 0; kk < KC; ++kk) {
            const float4 a0 = *(const float4*)(sW + kk*SW_LD + tm*8);
            const float4 a1 = *(const float4*)(sW + kk*SW_LD + tm*8 + 4);
            const float4 f0 = *(const float4*)(sF + kk*TN + tn*8);
            const float4 f1 = *(const float4*)(sF + kk*TN + tn*8 + 4);
            float av[8] = {a0.x,a0.y,a0.z,a0.w,a1.x,a1.y,a1.z,a1.w};
            float bv[8] = {f0.x,f0.y,f0.z,f0.w,f1.x,f1.y,f1.z,f1.w};
#pragma unroll
            for (int i = 0; i < 8; ++i)
#pragma unroll
                for (int j = 0; j < 8; ++j)
                    acc[i][j] = fmaf(av[i], bv[j], acc[i][j]);
        }
        __syncthreads();
    }

    float part[3][8];
#pragma unroll
    for (int r = 0; r < 3; ++r)
#pragma unroll
        for (int j = 0; j < 8; ++j) part[r][j] = 0.f;

#pragma unroll
    for (int i = 0; i < 8; ++i) {
        int m = tm*8 + i;
        float scale = __fdiv_rn(Gv[m], __fsqrt_rn(__fadd_rn(Vv[m], 1e-5f)));
        float shift = __fsub_rn(BEv[m], __fmul_rn(Mv[m], scale));
        float w0 = W2[m], w1 = W2[CC + m], w2 = W2[2*CC + m];
        float b1m = B1v[m];
#pragma unroll
        for (int j = 0; j < 8; ++j) {
            float x = __fadd_rn(acc[i][j], b1m);
            float y = __fadd_rn(__fmul_rn(x, scale), shift);
            float h = y > 0.f ? y : 0.f;
            part[0][j] = fmaf(w0, h, part[0][j]);
            part[1][j] = fmaf(w1, h, part[1][j]);
            part[2][j] = fmaf(w2, h, part[2][j]);
        }
    }
#pragma unroll
    for (int r = 0; r < 3; ++r) {
        float4 p0 = {part[r][0], part[r][1], part[r][2], part[r][3]};
        float4 p1 = {part[r][4], part[r][5], part[r][6], part[r][7]};
        *(float4*)(psum + (r*32 + tm)*PS_LD + tn*8)     = p0;
        *(float4*)(psum + (r*32 + tm)*PS_LD + tn*8 + 4) = p1;
    }
    __syncthreads();
    if (t < 192) {
        int r = t >> 6, col = t & 63;
        float s = 0.f;
#pragma unroll
        for (int w = 0; w < 32; ++w) s = __fadd_rn(s, psum[(r*32 + w)*PS_LD + col]);
        float tot = __fadd_rn(s, B2v[r]);
        gout[r*64 + col] = tot;
    }
    __syncthreads();
    if (t < 64) {
        int n = n0 + t;
        if (n < NN) {
            o0[(size_t)b*2*NN + n]      = gout[t];
            o0[(size_t)b*2*NN + NN + n] = gout[64 + t];
            o1[(size_t)b*NN + n]        = gout[128 + t];
        }
    }
}

// ---------------------------------------------------------------------------
// FPS helpers (R6-proven): u64-key DPP wave max, packed-pair scan
// ---------------------------------------------------------------------------
static constexpr int FPS_T = 256;
static constexpr int KAMAX = 20;
static constexpr int CAPA  = FPS_T * KAMAX; // 5120

template<int CTRL>
__device__ __forceinline__ unsigned long long dpp_umax(unsigned long long k) {
    int lo = __builtin_amdgcn_update_dpp(0, (int)(unsigned)k,         CTRL, 0xf, 0xf, false);
    int hi = __builtin_amdgcn_update_dpp(0, (int)(unsigned)(k >> 32), CTRL, 0xf, 0xf, false);
    unsigned long long ok = ((unsigned long long)(unsigned)hi << 32) | (unsigned)lo;
    return ok > k ? ok : k;
}

__device__ __forceinline__ unsigned long long wave_umax_dpp(unsigned long long k) {
    k = dpp_umax<0x111>(k);
    k = dpp_umax<0x112>(k);
    k = dpp_umax<0x114>(k);
    k = dpp_umax<0x118>(k);
    k = dpp_umax<0x142>(k);
    k = dpp_umax<0x143>(k);  // lane 63 has wave max
    return k;
}

__device__ __forceinline__ unsigned long long pack_key(float v, int i) {
    unsigned long long k = (((unsigned long long)__float_as_uint(v)) << 32)
                         | (unsigned long long)(0xFFFFFFFFu - (unsigned)i);
    return (v == -INFINITY) ? 0ull : k;
}

template<int KP>   // pairs of slots per thread
__device__ __forceinline__ void fps_scan_loop(
    int cnt, const float* __restrict__ sxyz,
    unsigned long long (*swk)[4], int* __restrict__ whist)
{
#pragma clang fp contract(off)
    const int t = threadIdx.x;
    const int wave = t >> 6, lane = t & 63;

    v2f X2[KP], Y2[KP], Z2[KP], D2[KP];
#pragma unroll
    for (int jp = 0; jp < KP; ++jp) {
        int g0 = t + ((2*jp) << 8);
        int g1 = g0 + 256;
        bool v0 = g0 < cnt, v1 = g1 < cnt;
        float4 wa = v0 ? *(const float4*)&sxyz[g0*4] : make_float4(0.f,0.f,0.f,0.f);
        float4 wb = v1 ? *(const float4*)&sxyz[g1*4] : make_float4(0.f,0.f,0.f,0.f);
        X2[jp][0] = wa.x; X2[jp][1] = wb.x;
        Y2[jp][0] = wa.y; Y2[jp][1] = wb.y;
        Z2[jp][0] = wa.z; Z2[jp][1] = wb.z;
        D2[jp][0] = v0 ? 1e10f : -INFINITY;
        D2[jp][1] = v1 ? 1e10f : -INFINITY;
    }

    float px = sxyz[0], py = sxyz[1], pz = sxyz[2];

    for (int it = 1; it < SS; ++it) {
        float bv = -INFINITY; int bi = 0x7fffffff;
#pragma unroll
        for (int jp = 0; jp < KP; ++jp) {
            v2f dx = X2[jp] - px;
            v2f dy = Y2[jp] - py;
            v2f dz = Z2[jp] - pz;
            v2f xx = dx*dx, yy = dy*dy;
            v2f sxy = xx + yy;
            v2f zz = dz*dz;
            v2f dd = sxy + zz;              // ((dx^2+dy^2)+dz^2), np order
            float dn0 = fminf(D2[jp][0], dd[0]);
            float dn1 = fminf(D2[jp][1], dd[1]);
            D2[jp][0] = dn0;
            D2[jp][1] = dn1;
            if (dn0 > bv) { bv = dn0; bi = t + ((2*jp)   << 8); }
            if (dn1 > bv) { bv = dn1; bi = t + ((2*jp+1) << 8); }
        }
        unsigned long long key = wave_umax_dpp(pack_key(bv, bi));
        int par = it & 1;
        if (lane == 63) swk[par][wave] = key;
        __syncthreads();
        const ulonglong2* kp = (const ulonglong2*)&swk[par][0];
        ulonglong2 kA = kp[0], kB = kp[1];
        unsigned long long m0 = kA.x > kA.y ? kA.x : kA.y;
        unsigned long long m1 = kB.x > kB.y ? kB.x : kB.y;
        unsigned long long best = m0 > m1 ? m0 : m1;
        int wi = (int)(0xFFFFFFFFu - (unsigned)(best & 0xFFFFFFFFull));
        float4 w4 = *(const float4*)&sxyz[wi*4];
        px = w4.x; py = w4.y; pz = w4.z;
        if (t == 0) whist[it] = wi;
    }
}

// ---------------------------------------------------------------------------
// MEGA kernel: 256 blocks x 256 threads, all co-resident (1 block/CU).
//  blocks [0,BB):   compact (mask from o0/o1) -> FPS -> publish inds (release)
//  blocks [BB,256): low-duty spin on done flag (keeps SCLK up through the
//                   fps window), then acquire and either
//                     wid<64:  gemm2 (indexed staging from feats via inds)
//                              + fused view-argmax + vp_rot epilogue
//                     else:    o2/o4/o5 gathers
// Cross-block handoff: __hip_atomic AGENT-scope release/acquire (covers
// cross-XCD L2 + stale lines from previous graph replay).
// ---------------------------------------------------------------------------
__global__ __launch_bounds__(256, 1) void mega_kernel(
    const float* __restrict__ xyz, const float* __restrict__ feats,
    const float* __restrict__ o0, const float* __restrict__ o1,
    const float* __restrict__ c1w, const float* __restrict__ c1b,
    const float* __restrict__ bng, const float* __restrict__ bnb,
    const float* __restrict__ bnm, const float* __restrict__ bnv,
    const float* __restrict__ c2w, const float* __restrict__ c2b,
    int* __restrict__ corig, float* __restrict__ cxg,
    float* __restrict__ cyg, float* __restrict__ czg,
    float* __restrict__ o2, float* __restrict__ o3, float* __restrict__ o4,
    float* __restrict__ o5, float* __restrict__ o6, float* __restrict__ o7,
    float* __restrict__ o8, int* __restrict__ indsp, int* __restrict__ donep)
{
    __shared__ alignas(16) char sm[86272];
    const int t = threadIdx.x;
    const int wave = t >> 6, lane = t & 63;

    if (blockIdx.x < BB) {
        // =================== FPS PRODUCER BLOCK ===================
        const int b = blockIdx.x;
        const size_t bofs = (size_t)b*NN;
        float* sxyz = (float*)sm;                                     // [CAPA*4]
        int*   whist = (int*)(sm + 81920);                            // [SS]
        unsigned long long (*swk)[4] = (unsigned long long (*)[4])(sm + 86016);
        int*   wsum  = (int*)(sm + 86080);                            // [4]
        int*   smisc = (int*)(sm + 86096);                            // running

        // ---- compact: mask recomputed bit-exactly from o0/o1 ----
        if (t == 0) smisc[0] = 0;
        __syncthreads();
        const float* ob0 = o0 + (size_t)b*2*NN;
        const float* ob1 = o1 + (size_t)b*NN;
        for (int base = 0; base < NN; base += 256) {
            int i = base + t;
            bool valid = i < NN;
            float g1 = valid ? ob1[i]      : 0.f;
            float v0 = valid ? ob0[i]      : 0.f;
            float v1 = valid ? ob0[NN + i] : 0.f;
            bool m = valid && (g1 > 0.1f) && (v1 > v0);
            unsigned long long bal = __ballot(m);
            int pre = __popcll(bal & ((1ull << lane) - 1ull));
            if (lane == 0) wsum[wave] = __popcll(bal);
            __syncthreads();
            int offs = smisc[0];
            int tilesum = wsum[0] + wsum[1] + wsum[2] + wsum[3];
            for (int ww = 0; ww < wave; ++ww) offs += wsum[ww];
            if (m) {
                int pos = offs + pre;
                float x = xyz[(bofs + i)*3 + 0];
                float y = xyz[(bofs + i)*3 + 1];
                float z = xyz[(bofs + i)*3 + 2];
                corig[bofs + pos] = i;
                cxg[bofs + pos] = x; cyg[bofs + pos] = y; czg[bofs + pos] = z;
                if (pos < CAPA) {
                    float4 w4 = {x, y, z, 0.f};
                    *(float4*)&sxyz[pos*4] = w4;
                }
            }
            __syncthreads();
            if (t == 0) smisc[0] += tilesum;   // no post-scatter wsum read (race-free)
        }
        __syncthreads();
        const int cnt = smisc[0];

        float* o3b = o3 + (size_t)b*SS;
        int*   oib = indsp + (size_t)b*SS;

        if (cnt <= 0) {
            for (int s = t; s < SS; s += FPS_T) { o3b[s] = 0.f; oib[s] = 0; }
            __syncthreads();
            if (t == 0) {
                __threadfence();
                __hip_atomic_fetch_add(donep, 1, __ATOMIC_RELEASE, __HIP_MEMORY_SCOPE_AGENT);
            }
            return;
        }

        if (t == 0) whist[0] = 0;
        __syncthreads();

        if (cnt <= CAPA) {
            int kat2 = ((cnt + 255) >> 8);
            kat2 = (kat2 + 1) & ~1;
            int kpn = kat2 >> 1;
            switch (kpn) {
                case 1:  fps_scan_loop<1 >(cnt, sxyz, swk, whist); break;
                case 2:  fps_scan_loop<2 >(cnt, sxyz, swk, whist); break;
                case 3:  fps_scan_loop<3 >(cnt, sxyz, swk, whist); break;
                case 4:  fps_scan_loop<4 >(cnt, sxyz, swk, whist); break;
                case 5:  fps_scan_loop<5 >(cnt, sxyz, swk, whist); break;
                case 6:  fps_scan_loop<6 >(cnt, sxyz, swk, whist); break;
                case 7:  fps_scan_loop<7 >(cnt, sxyz, swk, whist); break;
                case 8:  fps_scan_loop<8 >(cnt, sxyz, swk, whist); break;
                case 9:  fps_scan_loop<9 >(cnt, sxyz, swk, whist); break;
                default: fps_scan_loop<10>(cnt, sxyz, swk, whist); break;
            }
        } else {
            // fallback: LDS distances, streamed xyz from global compacted arrays
            float* Dl = sxyz;
            for (int g = t; g < cnt; g += FPS_T) Dl[g] = 1e10f;
            __syncthreads();
            float px = cxg[bofs], py = cyg[bofs], pz = czg[bofs];
            for (int it = 1; it < SS; ++it) {
                float bv = -INFINITY; int bi = 0x7fffffff;
                for (int g = t; g < cnt; g += FPS_T) {
                    float dx = __fsub_rn(cxg[bofs + g], px);
                    float dy = __fsub_rn(cyg[bofs + g], py);
                    float dz = __fsub_rn(czg[bofs + g], pz);
                    float d  = __fadd_rn(__fadd_rn(__fmul_rn(dx,dx), __fmul_rn(dy,dy)), __fmul_rn(dz,dz));
                    float dn = fminf(Dl[g], d);
                    Dl[g] = dn;
                    if (dn > bv) { bv = dn; bi = g; }
                }
                unsigned long long key = wave_umax_dpp(pack_key(bv, bi));
                int par = it & 1;
                if (lane == 63) swk[par][wave] = key;
                __syncthreads();
                const ulonglong2* kp = (const ulonglong2*)&swk[par][0];
                ulonglong2 kA = kp[0], kB = kp[1];
                unsigned long long m0 = kA.x > kA.y ? kA.x : kA.y;
                unsigned long long m1 = kB.x > kB.y ? kB.x : kB.y;
                unsigned long long best = m0 > m1 ? m0 : m1;
                int wi = (int)(0xFFFFFFFFu - (unsigned)(best & 0xFFFFFFFFull));
                px = cxg[bofs + wi]; py = cyg[bofs + wi]; pz = czg[bofs + wi];
                if (t == 0) whist[it] = wi;
            }
        }

        __syncthreads();
        for (int s = t; s < SS; s += FPS_T) {
            int wi  = whist[s];
            int org = corig[bofs + wi];
            oib[s] = org;
            o3b[s] = (float)org;
        }
        __syncthreads();                 // all inds writes issued & drained
        if (t == 0) {
            __threadfence();             // agent-scope flush of this block's stores
            __hip_atomic_fetch_add(donep, 1, __ATOMIC_RELEASE, __HIP_MEMORY_SCOPE_AGENT);
        }
        return;
    }

    // =================== CONSUMER BLOCKS ===================
    {
        int* smisc = (int*)(sm + 86096);
        if (t == 0) smisc[1] = 0;
        __syncthreads();
        // low-duty spin (R4/R6-proven clock-friendly point)
        float a = 1.0f + (float)t * 1e-6f, bmul = 1.0000001f, c = 0.f;
        for (int iter = 0; iter < (1 << 22); ++iter) {
#pragma unroll
            for (int u = 0; u < 16; ++u) c = fmaf(a, bmul, c);
            __builtin_amdgcn_s_sleep(8);
            if (t == 0 && (iter & 7) == 0) {
                if (__hip_atomic_load(donep, __ATOMIC_RELAXED, __HIP_MEMORY_SCOPE_AGENT) >= BB)
                    *(volatile int*)&smisc[1] = 1;
            }
            if (*(volatile int*)&smisc[1]) break;
        }
        ((volatile float*)sm)[32 + (t & 31)] = c;   // keep spin live; region reused later
        __syncthreads();
        (void)__hip_atomic_load(donep, __ATOMIC_ACQUIRE, __HIP_MEMORY_SCOPE_AGENT);
    }

    const int wid = blockIdx.x - BB;

    if (wid < 64) {
        // ---------------- gemm2 + view/rot for one 64-col tile ----------------
        const int bi = wid >> 4;
        const int n0 = (wid & 15) << 6;
        float* sW   = (float*)sm;                          // [KC][SW_LD]
        float* sF   = (float*)(sm + KC*SW_LD*4);           // [KC][TN]
        float* psum = (float*)sm;                          // [3][32][PS_LD]
        float* gout = (float*)(sm + 3*32*PS_LD*4);         // [3][64]
        float* tv   = (float*)(sm + KC*SW_LD*4);           // [3][300] (aliases sF, post-k-loop)
        int*   sIdx = (int*)(sm + 81920);                  // [64]

        if (t < 64) sIdx[t] = indsp[(bi << 10) + n0 + t];
        __syncthreads();

        const int tm = t & 31;
        const int tn = t >> 5;

        float acc[8][8];
#pragma unroll
        for (int i = 0; i < 8; ++i)
#pragma unroll
            for (int j = 0; j < 8; ++j) acc[i][j] = 0.f;

        for (int k0 = 0; k0 < CC; k0 += KC) {
#pragma unroll
            for (int r = 0; r < (CC*KC)/256; ++r) {
                int idx = r*256 + t;
                int m  = idx >> 5;
                int kk = idx & 31;
                sW[kk*SW_LD + m] = c1w[m*CC + k0 + kk];
            }
#pragma unroll
            for (int r = 0; r < (KC*TN)/256; ++r) {
                int idx = r*256 + t;
                int kk = idx >> 6;
                int j  = idx & 63;
                sF[kk*TN + j] = feats[((size_t)bi*CC + k0 + kk)*NN + sIdx[j]];
            }
            __syncthreads();
#pragma unroll 8
            for (int kk = 0; kk < KC; ++kk) {
                const float4 a0 = *(const float4*)(sW + kk*SW_LD + tm*8);
                const float4 a1 = *(const float4*)(sW + kk*SW_LD + tm*8 + 4);
                const float4 f0 = *(const float4*)(sF + kk*TN + tn*8);
                const float4 f1 = *(const float4*)(sF + kk*TN + tn*8 + 4);
                float av[8] = {a0.x,a0.y,a0.z,a0.w,a1.x,a1.y,a1.z,a1.w};
                float bv[8] = {f0.x,f0.y,f0.z,f0.w,f1.x,f1.y,f1.z,f1.w};
#pragma unroll
                for (int i = 0; i < 8; ++i)
#pragma unroll
                    for (int j = 0; j < 8; ++j)
                        acc[i][j] = fmaf(av[i], bv[j], acc[i][j]);
            }
            __syncthreads();
        }

        float part[3][8];
#pragma unroll
        for (int r = 0; r < 3; ++r)
#pragma unroll
            for (int j = 0; j < 8; ++j) part[r][j] = 0.f;

#pragma unroll
        for (int i = 0; i < 8; ++i) {
            int m = tm*8 + i;
            float scale = __fdiv_rn(bng[m], __fsqrt_rn(__fadd_rn(bnv[m], 1e-5f)));
            float shift = __fsub_rn(bnb[m], __fmul_rn(bnm[m], scale));
            float w0 = c2w[m], w1 = c2w[CC + m], w2 = c2w[2*CC + m];
            float b1m = c1b[m];
#pragma unroll
            for (int j = 0; j < 8; ++j) {
                float x = __fadd_rn(acc[i][j], b1m);
                float y = __fadd_rn(__fmul_rn(x, scale), shift);
                float h = y > 0.f ? y : 0.f;
                part[0][j] = fmaf(w0, h, part[0][j]);
                part[1][j] = fmaf(w1, h, part[1][j]);
                part[2][j] = fmaf(w2, h, part[2][j]);
            }
        }
#pragma unroll
        for (int r = 0; r < 3; ++r) {
            float4 p0 = {part[r][0], part[r][1], part[r][2], part[r][3]};
            float4 p1 = {part[r][4], part[r][5], part[r][6], part[r][7]};
            *(float4*)(psum + (r*32 + tm)*PS_LD + tn*8)     = p0;
            *(float4*)(psum + (r*32 + tm)*PS_LD + tn*8 + 4) = p1;
        }
        __syncthreads();
        if (t < 192) {
            int r = t >> 6, col = t & 63;
            float s = 0.f;
#pragma unroll
            for (int w = 0; w < 32; ++w) s = __fadd_rn(s, psum[(r*32 + w)*PS_LD + col]);
            float tot = __fadd_rn(s, c2b[r]);
            gout[r*64 + col] = tot;
            o6[((size_t)bi*SS + n0 + col)*3 + r] = tot;
        }
        __syncthreads();
        // template views (exact double math, cast to f32 — matches _grasp_views)
        for (int i = t; i < NV; i += 256) {
            double phi = (sqrt(5.0) - 1.0) * 0.5;
            double zd  = (2.0*(double)i + 1.0)/300.0 - 1.0;
            double rr  = sqrt(fmax(1.0 - zd*zd, 0.0));
            double ang = 2.0 * 3.14159265358979323846 * (double)i * phi;
            float fx = (float)(rr * cos(ang));
            float fy = (float)(rr * sin(ang));
            float fz = (float)zd;
            float nr = __fsqrt_rn(__fadd_rn(__fadd_rn(__fmul_rn(fx,fx), __fmul_rn(fy,fy)), __fmul_rn(fz,fz)));
            float dn = fmaxf(nr, 1e-8f);
            tv[i]       = __fdiv_rn(fx, dn);
            tv[NV + i]  = __fdiv_rn(fy, dn);
            tv[2*NV + i]= __fdiv_rn(fz, dn);
        }
        __syncthreads();
        if (t < 64) {
            int col = t;
            int sg = bi*SS + n0 + col;
            float vx = gout[col], vy = gout[64 + col], vz = gout[128 + col];

            float nr = __fsqrt_rn(__fadd_rn(__fadd_rn(__fmul_rn(vx,vx), __fmul_rn(vy,vy)), __fmul_rn(vz,vz)));
            float dn = fmaxf(nr, 1e-8f);
            float ux = __fdiv_rn(vx, dn), uy = __fdiv_rn(vy, dn), uz = __fdiv_rn(vz, dn);
            float best = -INFINITY; int bidx = 0;
            for (int v = 0; v < NV; ++v) {
                float cde = __fadd_rn(__fadd_rn(__fmul_rn(ux, tv[v]), __fmul_rn(uy, tv[NV+v])), __fmul_rn(uz, tv[2*NV+v]));
                if (cde > best) { best = cde; bidx = v; }
            }
            o7[sg] = (float)bidx;

            float axx = -vx, axy = -vy, axz = -vz;
            float ayx = vy, ayy = -vx, ayz = 0.f;
            float s2 = __fadd_rn(__fadd_rn(__fmul_rn(ayx,ayx), __fmul_rn(ayy,ayy)), 0.f);
            if (s2 == 0.f) { ayx = 0.f; ayy = 1.f; ayz = 0.f; }
            float an = __fsqrt_rn(__fadd_rn(__fadd_rn(__fmul_rn(axx,axx), __fmul_rn(axy,axy)), __fmul_rn(axz,axz)));
            float nx0 = __fdiv_rn(axx, an), nx1 = __fdiv_rn(axy, an), nx2 = __fdiv_rn(axz, an);
            float bn2 = __fsqrt_rn(__fadd_rn(__fadd_rn(__fmul_rn(ayx,ayx), __fmul_rn(ayy,ayy)), __fmul_rn(ayz,ayz)));
            float ny0 = __fdiv_rn(ayx, bn2), ny1 = __fdiv_rn(ayy, bn2), ny2 = __fdiv_rn(ayz, bn2);
            float nz0 = __fsub_rn(__fmul_rn(nx1, ny2), __fmul_rn(nx2, ny1));
            float nz1 = __fsub_rn(__fmul_rn(nx2, ny0), __fmul_rn(nx0, ny2));
            float nz2 = __fsub_rn(__fmul_rn(nx0, ny1), __fmul_rn(nx1, ny0));
            size_t o = (size_t)sg * 9;
            o8[o+0] = nx0; o8[o+1] = ny0; o8[o+2] = nz0;
            o8[o+3] = nx1; o8[o+4] = ny1; o8[o+5] = nz1;
            o8[o+6] = nx2; o8[o+7] = ny2; o8[o+8] = nz2;
        }
    } else {
        // ---------------- gathers: o2 / o4 / o5 (188 blocks) ----------------
        const int NQ = (BB*CC*SS) / 4;          // 262144 quads
        for (int q = (wid - 64)*256 + t; q < NQ; q += 188*256) {
            int e = q << 2;
            int b = e >> 18;
            int r = e & ((1 << 18) - 1);
            int c = r >> 10;
            int s = r & 1023;
            int4 i4 = *(const int4*)&indsp[(b << 10) + s];
            const float* fb = feats + ((size_t)b*CC + c)*NN;
            float4 v = { fb[i4.x], fb[i4.y], fb[i4.z], fb[i4.w] };
            *(float4*)&o4[e] = v;
            if (c == 0) {
                const float* gb = o1 + (size_t)b*NN;
                float4 g4 = { gb[i4.x], gb[i4.y], gb[i4.z], gb[i4.w] };
                *(float4*)&o5[(b << 10) + s] = g4;
                const float* xb = xyz + (size_t)b*NN*3;
                float o2buf[12];
                int ii[4] = { i4.x, i4.y, i4.z, i4.w };
#pragma unroll
                for (int k = 0; k < 4; ++k) {
                    o2buf[k*3+0] = xb[(size_t)ii[k]*3 + 0];
                    o2buf[k*3+1] = xb[(size_t)ii[k]*3 + 1];
                    o2buf[k*3+2] = xb[(size_t)ii[k]*3 + 2];
                }
                float* dst = o2 + ((size_t)(b << 10) + s)*3;
                *(float4*)&dst[0] = *(float4*)&o2buf[0];
                *(float4*)&dst[4] = *(float4*)&o2buf[4];
                *(float4*)&dst[8] = *(float4*)&o2buf[8];
            }
        }
    }
}

// ---------------------------------------------------------------------------
extern "C" void kernel_launch(void* const* d_in, const int* in_sizes, int n_in,
                              void* d_out, int out_size, void* d_ws, size_t ws_size,
                              hipStream_t stream) {
    const float* xyz   = (const float*)d_in[0];
    const float* feats = (const float*)d_in[1];
    const float* gh_w1 = (const float*)d_in[2];
    const float* gh_b1 = (const float*)d_in[3];
    const float* gh_g  = (const float*)d_in[4];
    const float* gh_be = (const float*)d_in[5];
    const float* gh_m  = (const float*)d_in[6];
    const float* gh_v  = (const float*)d_in[7];
    const float* gh_w2 = (const float*)d_in[8];
    const float* gh_b2 = (const float*)d_in[9];
    const float* c1_w  = (const float*)d_in[10];
    const float* c1_b  = (const float*)d_in[11];
    const float* bn_g  = (const float*)d_in[12];
    const float* bn_b  = (const float*)d_in[13];
    const float* bn_m  = (const float*)d_in[14];
    const float* bn_v  = (const float*)d_in[15];
    const float* c2_w  = (const float*)d_in[16];
    const float* c2_b  = (const float*)d_in[17];

    float* out = (float*)d_out;
    float* o0 = out + O0;
    float* o1 = out + O1;
    float* o2 = out + O2;
    float* o3 = out + O3;
    float* o4 = out + O4;
    float* o5 = out + O5;
    float* o6 = out + O6;
    float* o7 = out + O7;
    float* o8 = out + O8;

    char* ws = (char*)d_ws;
    size_t off = 0;
    auto take = [&](size_t bytes) -> char* {
        char* p = ws + off;
        off = (off + bytes + 255) & ~(size_t)255;
        return p;
    };
    int*   corig = (int*)take((size_t)BB*NN*4);
    float* cx    = (float*)take((size_t)BB*NN*4);
    float* cy    = (float*)take((size_t)BB*NN*4);
    float* cz    = (float*)take((size_t)BB*NN*4);
    int*   indsp = (int*)take((size_t)BB*SS*4);
    int*   donep = (int*)take(64);

    // 1) fused conv+bn+relu+conv over all N points -> o0, o1
    gemm_fused<<<dim3((NN + TN - 1)/TN, BB), 256, 0, stream>>>(
        feats, gh_w1, gh_b1, gh_g, gh_be, gh_m, gh_v, gh_w2, gh_b2, o0, o1);

    // 2) mega: compact+FPS (4 blocks) || spin -> gemm2+view (64) & gathers (188)
    hipMemsetAsync(donep, 0, 4, stream);
    mega_kernel<<<dim3(256), 256, 0, stream>>>(
        xyz, feats, o0, o1,
        c1_w, c1_b, bn_g, bn_b, bn_m, bn_v, c2_w, c2_b,
        corig, cx, cy, cz,
        o2, o3, o4, o5, o6, o7, o8, indsp, donep);
}